// Round 6
// baseline (271.240 us; speedup 1.0000x reference)
//
#include <hip/hip_runtime.h>
#include <hip/hip_bf16.h>

#define DEV __device__ __forceinline__

typedef __attribute__((ext_vector_type(8))) short bf16x8;
typedef __attribute__((ext_vector_type(4))) float f32x4;

// Problem constants
#define BB 4
#define SS 2048
#define DD 1024
#define HH 16
#define HDD 64
#define MM (BB * SS)   // 8192
#define NT (SS / 64)   // 32 q-tiles per (b,h)

DEV short f2bf(float f) {
  unsigned u = __builtin_bit_cast(unsigned, f);
  u = u + 0x7fffu + ((u >> 16) & 1u);
  return (short)(u >> 16);
}

DEV float fexp2(float x) {  // raw v_exp_f32 (2^x)
  float r;
  asm("v_exp_f32 %0, %1" : "=v"(r) : "v"(x));
  return r;
}
DEV float frcp(float x) {
  float r;
  asm("v_rcp_f32 %0, %1" : "=v"(r) : "v"(x));
  return r;
}
DEV unsigned cvtpk(float a, float b) {  // {lo:bf16(a), hi:bf16(b)}
  unsigned r;
  asm("v_cvt_pk_bf16_f32 %0, %1, %2" : "=v"(r) : "v"(a), "v"(b));
  return r;
}

DEV void gload_lds16(const void* g, void* l) {
  __builtin_amdgcn_global_load_lds((const __attribute__((address_space(1))) void*)g,
                                   (__attribute__((address_space(3))) void*)l, 16, 0, 0);
}

// DPP 16-lane reductions (VALU pipe; avoids ds_swizzle dependent-latency chains)
template<int CTRL> DEV float dpp_maxstep(float v) {
  int s = __builtin_amdgcn_update_dpp(0, __builtin_bit_cast(int, v), CTRL, 0xF, 0xF, true);
  return fmaxf(v, __builtin_bit_cast(float, s));
}
template<int CTRL> DEV float dpp_addstep(float v) {
  int s = __builtin_amdgcn_update_dpp(0, __builtin_bit_cast(int, v), CTRL, 0xF, 0xF, true);
  return v + __builtin_bit_cast(float, s);
}
DEV float redmax16(float v) {
  v = dpp_maxstep<0xB1>(v);
  v = dpp_maxstep<0x4E>(v);
  v = dpp_maxstep<0x141>(v);
  v = dpp_maxstep<0x140>(v);
  return v;
}
DEV float redsum16(float v) {
  v = dpp_addstep<0xB1>(v);
  v = dpp_addstep<0x4E>(v);
  v = dpp_addstep<0x141>(v);
  v = dpp_addstep<0x140>(v);
  return v;
}

__global__ __launch_bounds__(256)
void cast_f32_bf16(const float* __restrict__ in, unsigned long long* __restrict__ out, int n4) {
  int i = blockIdx.x * 256 + threadIdx.x;
  const int st = gridDim.x * 256;
  for (; i < n4; i += st) {
    const float4 f = ((const float4*)in)[i];
    unsigned long long a = (unsigned long long)(unsigned short)f2bf(f.x)
        | ((unsigned long long)(unsigned short)f2bf(f.y) << 16)
        | ((unsigned long long)(unsigned short)f2bf(f.z) << 32)
        | ((unsigned long long)(unsigned short)f2bf(f.w) << 48);
    out[i] = a;
  }
}

// C = A[M,K] * Bw[N,K]^T + bias.  EPI=0: scatter to Q/K/V bf16 ws. EPI=1: f32 out.
// Q pre-scaled by (1/sqrt(HD))*log2(e): attention softmax runs in exp2 domain.
template<int EPI>
__global__ __launch_bounds__(256)
void gemm_bt(const short* __restrict__ A, const short* __restrict__ Bw,
             const float* __restrict__ bias,
             short* __restrict__ qo, short* __restrict__ ko, short* __restrict__ vo,
             float* __restrict__ co,
             int M, int N, int K) {
  __shared__ short sA[128 * 64];
  __shared__ short sB[128 * 64];
  const int lane = threadIdx.x & 63;
  const int wv = threadIdx.x >> 6;
  const int wm = wv >> 1, wn = wv & 1;
  const int m0 = blockIdx.y * 128;
  const int n0 = blockIdx.x * 128;
  f32x4 acc[4][4] = {};
  const int nkt = K >> 6;
  for (int kt = 0; kt < nkt; ++kt) {
    const int k0 = kt << 6;
    if (kt) __syncthreads();
#pragma unroll
    for (int i = 0; i < 4; ++i) {
      const int c = i * 4 + wv;
      const int b = c * 1024 + lane * 16;
      const int row = b >> 7;
      const int colb = b & 127;
      gload_lds16((const char*)A + ((size_t)(m0 + row) * K + k0) * 2 + colb,
                  (char*)sA + c * 1024);
      gload_lds16((const char*)Bw + ((size_t)(n0 + row) * K + k0) * 2 + colb,
                  (char*)sB + c * 1024);
    }
    __syncthreads();
#pragma unroll
    for (int ks = 0; ks < 2; ++ks) {
      bf16x8 af[4], bf_[4];
#pragma unroll
      for (int i = 0; i < 4; ++i) {
        af[i]  = *(const bf16x8*)&sA[(wm * 64 + i * 16 + (lane & 15)) * 64 + ks * 32 + (lane >> 4) * 8];
        bf_[i] = *(const bf16x8*)&sB[(wn * 64 + i * 16 + (lane & 15)) * 64 + ks * 32 + (lane >> 4) * 8];
      }
#pragma unroll
      for (int i = 0; i < 4; ++i)
#pragma unroll
        for (int j = 0; j < 4; ++j)
          acc[i][j] = __builtin_amdgcn_mfma_f32_16x16x32_bf16(af[i], bf_[j], acc[i][j], 0, 0, 0);
    }
  }
#pragma unroll
  for (int i = 0; i < 4; ++i) {
#pragma unroll
    for (int j = 0; j < 4; ++j) {
#pragma unroll
      for (int r = 0; r < 4; ++r) {
        const int row = m0 + wm * 64 + i * 16 + (lane >> 4) * 4 + r;
        const int col = n0 + wn * 64 + j * 16 + (lane & 15);
        float v = acc[i][j][r] + bias[col];
        if (EPI == 0) {
          const int part = col >> 10, oo = col & 1023;
          const int h = oo >> 6, d = oo & 63;
          const int bb = row >> 11, s = row & 2047;
          if (part == 0)
            qo[(((size_t)bb * HH + h) * SS + s) * HDD + d] = f2bf(v * 0.18033688f); // 0.125*log2(e)
          else if (part == 1)
            ko[(((size_t)bb * HH + h) * SS + s) * HDD + d] = f2bf(v);
          else
            vo[(((size_t)bb * HH + h) * HDD + d) * SS + s] = f2bf(v);
        } else {
          co[(size_t)row * N + col] = v;
        }
      }
    }
  }
}

// Flash attention v6 (= v5 + f32 P round-trip, cvt_pk on read side):
// grid (NT/2, B*H), 256 threads (4 waves x 16 q-rows); paired q-tiles
// {bx, NT-1-bx} -> 33 tiles/block uniform. K/V double-buffered in LDS via
// global_load_lds (XOR-swizzled source / swizzled read, rule #21). Softmax in
// exp2 domain, DPP reductions, defer-max (T13). P goes through LDS as raw f32
// (no per-element f2bf storm); consumer packs with v_cvt_pk_bf16_f32 (8/tile).
__global__ __launch_bounds__(256)
void attn_fwd(const short* __restrict__ Q, const short* __restrict__ K,
              const short* __restrict__ V, short* __restrict__ Y) {
  __shared__ short sK[2][64 * 64];
  __shared__ short sV[2][64 * 64];
  __shared__ float sPf[64][67];   // stride 67 f32: ~2-way read conflicts (free)
  const int bh = blockIdx.y;
  const int tid = threadIdx.x, lane = tid & 63, w = tid >> 6;
  const size_t bqk = (size_t)bh * (SS * HDD);
  const size_t bv  = (size_t)bh * (HDD * SS);
  const int b = bh >> 4, h = bh & 15;
  const int lr = lane & 15;        // fragment row/col index
  const int lg = lane >> 4;        // k-group

  // staging geometry: element e (0..511), 16B each; LDS dest linear,
  // global source slot pre-swizzled s = (e&7)^(row&7)
  const int e0 = w * 64 + lane;
  const int e1 = 256 + e0;
  const int r0 = e0 >> 3, s0 = ((e0 & 7) ^ (r0 & 7)) * 8;
  const int r1 = e1 >> 3, s1 = ((e1 & 7) ^ (r1 & 7)) * 8;

  for (int qsel = 0; qsel < 2; ++qsel) {
    const int qb = qsel ? (NT - 1 - blockIdx.x) : blockIdx.x;
    const int q0 = qb * 64;

    __syncthreads();   // protect buffer re-stage vs previous q-tile's reads

    // prologue: stage tile 0 into buffer 0
    {
      const short* gK = K + bqk;
      const short* gV = V + bv;
      gload_lds16(gK + (size_t)r0 * HDD + s0, &sK[0][e0 * 8]);
      gload_lds16(gV + (size_t)r0 * SS + s0, &sV[0][e0 * 8]);
      gload_lds16(gK + (size_t)r1 * HDD + s1, &sK[0][e1 * 8]);
      gload_lds16(gV + (size_t)r1 * SS + s1, &sV[0][e1 * 8]);
    }

    bf16x8 qf[2];
#pragma unroll
    for (int ks = 0; ks < 2; ++ks)
      qf[ks] = *(const bf16x8*)&Q[bqk + (size_t)(q0 + w * 16 + lr) * HDD + ks * 32 + lg * 8];

    f32x4 accO[4] = {};
    float m_[4], l_[4];
#pragma unroll
    for (int r = 0; r < 4; ++r) { m_[r] = -1e30f; l_[r] = 0.f; }

    int cur = 0;
    for (int kt = 0; kt <= qb; ++kt) {
      const int kc0 = kt * 64;
      __syncthreads();   // staged tile ready (vmcnt drained); prev reads done
      if (kt < qb) {     // stage next tile into the other buffer
        const short* gK = K + bqk + (size_t)(kc0 + 64) * 64;
        const short* gV = V + bv + kc0 + 64;
        gload_lds16(gK + (size_t)r0 * HDD + s0, &sK[cur ^ 1][e0 * 8]);
        gload_lds16(gV + (size_t)r0 * SS + s0, &sV[cur ^ 1][e0 * 8]);
        gload_lds16(gK + (size_t)r1 * HDD + s1, &sK[cur ^ 1][e1 * 8]);
        gload_lds16(gV + (size_t)r1 * SS + s1, &sV[cur ^ 1][e1 * 8]);
      }

      f32x4 sc_[4] = {};
#pragma unroll
      for (int ks = 0; ks < 2; ++ks) {
#pragma unroll
        for (int nf = 0; nf < 4; ++nf) {
          const int row = nf * 16 + lr;
          const bf16x8 kf = *(const bf16x8*)&sK[cur][row * 64 + (((ks << 2) + lg) ^ (lr & 7)) * 8];
          sc_[nf] = __builtin_amdgcn_mfma_f32_16x16x32_bf16(qf[ks], kf, sc_[nf], 0, 0, 0);
        }
      }
      if (kt == qb) {   // diagonal tile: causal mask
#pragma unroll
        for (int nf = 0; nf < 4; ++nf)
#pragma unroll
          for (int r = 0; r < 4; ++r) {
            const int col = kc0 + nf * 16 + lr;
            const int row = q0 + w * 16 + lg * 4 + r;
            if (col > row) sc_[nf][r] = -1e30f;
          }
      }

      // tile row-max (DPP); defer-max: rescale only if it beats m_ by >8*log2e
      float rmv[4];
      bool need = false;
#pragma unroll
      for (int r = 0; r < 4; ++r) {
        float rm = fmaxf(fmaxf(sc_[0][r], sc_[1][r]), fmaxf(sc_[2][r], sc_[3][r]));
        rm = redmax16(rm);
        rmv[r] = rm;
        need = need || (rm > m_[r] + 11.5416f);
      }
      if (__any(need)) {
#pragma unroll
        for (int r = 0; r < 4; ++r) {
          const float mn = fmaxf(m_[r], rmv[r]);
          const float scale = fexp2(m_[r] - mn);
          m_[r] = mn;
          l_[r] *= scale;
#pragma unroll
          for (int df = 0; df < 4; ++df) accO[df][r] *= scale;
        }
      }
#pragma unroll
      for (int r = 0; r < 4; ++r) {
        float rs = 0.f;
#pragma unroll
        for (int nf = 0; nf < 4; ++nf) {
          const float p = fexp2(sc_[nf][r] - m_[r]);
          sc_[nf][r] = p;
          rs += p;
        }
        l_[r] += redsum16(rs);
      }

      // P round-trip through wave-private LDS rows as RAW F32 (no f2bf storm)
#pragma unroll
      for (int nf = 0; nf < 4; ++nf)
#pragma unroll
        for (int r = 0; r < 4; ++r)
          sPf[w * 16 + lg * 4 + r][nf * 16 + lr] = sc_[nf][r];

      const float* prow = &sPf[w * 16 + lr][0];
#pragma unroll
      for (int ks = 0; ks < 2; ++ks) {
        const f32x4 pa = *(const f32x4*)&prow[ks * 32 + lg * 8];
        const f32x4 pb = *(const f32x4*)&prow[ks * 32 + lg * 8 + 4];
        int4 pw;
        pw.x = (int)cvtpk(pa[0], pa[1]);
        pw.y = (int)cvtpk(pa[2], pa[3]);
        pw.z = (int)cvtpk(pb[0], pb[1]);
        pw.w = (int)cvtpk(pb[2], pb[3]);
        const bf16x8 pf = __builtin_bit_cast(bf16x8, pw);
#pragma unroll
        for (int df = 0; df < 4; ++df) {
          const int row = df * 16 + lr;
          const bf16x8 vf = *(const bf16x8*)&sV[cur][row * 64 + (((ks << 2) + lg) ^ (lr & 7)) * 8];
          accO[df] = __builtin_amdgcn_mfma_f32_16x16x32_bf16(pf, vf, accO[df], 0, 0, 0);
        }
      }
      cur ^= 1;
    }
#pragma unroll
    for (int r = 0; r < 4; ++r) {
      const float inv = frcp(l_[r]);
      const int srow = q0 + w * 16 + lg * 4 + r;
#pragma unroll
      for (int df = 0; df < 4; ++df) {
        const int dcol = h * HDD + df * 16 + lr;
        Y[((size_t)b * SS + srow) * DD + dcol] = f2bf(accO[df][r] * inv);
      }
    }
  }
}

extern "C" void kernel_launch(void* const* d_in, const int* in_sizes, int n_in,
                              void* d_out, int out_size, void* d_ws, size_t ws_size,
                              hipStream_t stream) {
  const float* x     = (const float*)d_in[0];
  const float* w_qkv = (const float*)d_in[1];
  const float* b_qkv = (const float*)d_in[2];
  const float* w_out = (const float*)d_in[3];
  const float* b_out = (const float*)d_in[4];
  float* out = (float*)d_out;

  const size_t nx = (size_t)MM * DD;        // 8388608
  const size_t nwq = (size_t)3 * DD * DD;   // 3145728
  const size_t nwo = (size_t)DD * DD;       // 1048576

  short* x_bf    = (short*)d_ws;
  short* wqkv_bf = x_bf + nx;
  short* wout_bf = wqkv_bf + nwq;
  short* q_ws    = wout_bf + nwo;
  short* k_ws    = q_ws + nx;
  short* v_ws    = k_ws + nx;
  short* y_ws    = v_ws + nx;

  cast_f32_bf16<<<dim3(2048), dim3(256), 0, stream>>>(x, (unsigned long long*)x_bf, (int)(nx / 4));
  cast_f32_bf16<<<dim3(1024), dim3(256), 0, stream>>>(w_qkv, (unsigned long long*)wqkv_bf, (int)(nwq / 4));
  cast_f32_bf16<<<dim3(512), dim3(256), 0, stream>>>(w_out, (unsigned long long*)wout_bf, (int)(nwo / 4));

  gemm_bt<0><<<dim3(3 * DD / 128, MM / 128), dim3(256), 0, stream>>>(
      x_bf, wqkv_bf, b_qkv, q_ws, k_ws, v_ws, nullptr, MM, 3 * DD, DD);

  attn_fwd<<<dim3(NT / 2, BB * HH), dim3(256), 0, stream>>>(q_ws, k_ws, v_ws, y_ws);

  gemm_bt<1><<<dim3(DD / 128, MM / 128), dim3(256), 0, stream>>>(
      y_ws, wout_bf, b_out, nullptr, nullptr, nullptr, out, MM, DD, DD);
}

// Round 7
// 229.868 us; speedup vs baseline: 1.1800x; 1.1800x over previous
//
#include <hip/hip_runtime.h>
#include <hip/hip_bf16.h>

#define DEV __device__ __forceinline__

typedef __attribute__((ext_vector_type(8))) short bf16x8;
typedef __attribute__((ext_vector_type(4))) float f32x4;

// Problem constants
#define BB 4
#define SS 2048
#define DD 1024
#define HH 16
#define HDD 64
#define MM (BB * SS)   // 8192
#define NT (SS / 64)   // 32 q-tiles per (b,h)

DEV short f2bf(float f) {
  unsigned u = __builtin_bit_cast(unsigned, f);
  u = u + 0x7fffu + ((u >> 16) & 1u);
  return (short)(u >> 16);
}

DEV float fexp2(float x) {  // raw v_exp_f32 (2^x)
  float r;
  asm("v_exp_f32 %0, %1" : "=v"(r) : "v"(x));
  return r;
}
DEV float frcp(float x) {
  float r;
  asm("v_rcp_f32 %0, %1" : "=v"(r) : "v"(x));
  return r;
}
DEV unsigned cvtpk(float a, float b) {  // {lo:bf16(a), hi:bf16(b)}
  unsigned r;
  asm("v_cvt_pk_bf16_f32 %0, %1, %2" : "=v"(r) : "v"(a), "v"(b));
  return r;
}

DEV void gload_lds16(const void* g, void* l) {
  __builtin_amdgcn_global_load_lds((const __attribute__((address_space(1))) void*)g,
                                   (__attribute__((address_space(3))) void*)l, 16, 0, 0);
}

__global__ __launch_bounds__(256)
void cast_f32_bf16(const float* __restrict__ in, unsigned long long* __restrict__ out, int n4) {
  int i = blockIdx.x * 256 + threadIdx.x;
  const int st = gridDim.x * 256;
  for (; i < n4; i += st) {
    const float4 f = ((const float4*)in)[i];
    unsigned long long a = (unsigned long long)(unsigned short)f2bf(f.x)
        | ((unsigned long long)(unsigned short)f2bf(f.y) << 16)
        | ((unsigned long long)(unsigned short)f2bf(f.z) << 32)
        | ((unsigned long long)(unsigned short)f2bf(f.w) << 48);
    out[i] = a;
  }
}

// C = A[M,K] * Bw[N,K]^T + bias.  EPI=0: scatter to Q/K/V bf16 ws. EPI=1: f32 out.
// Q pre-scaled by (1/sqrt(HD))*log2(e): attention softmax runs in exp2 domain.
template<int EPI>
__global__ __launch_bounds__(256)
void gemm_bt(const short* __restrict__ A, const short* __restrict__ Bw,
             const float* __restrict__ bias,
             short* __restrict__ qo, short* __restrict__ ko, short* __restrict__ vo,
             float* __restrict__ co,
             int M, int N, int K) {
  __shared__ short sA[128 * 64];
  __shared__ short sB[128 * 64];
  const int lane = threadIdx.x & 63;
  const int wv = threadIdx.x >> 6;
  const int wm = wv >> 1, wn = wv & 1;
  const int m0 = blockIdx.y * 128;
  const int n0 = blockIdx.x * 128;
  f32x4 acc[4][4] = {};
  const int nkt = K >> 6;
  for (int kt = 0; kt < nkt; ++kt) {
    const int k0 = kt << 6;
    if (kt) __syncthreads();
#pragma unroll
    for (int i = 0; i < 4; ++i) {
      const int c = i * 4 + wv;
      const int b = c * 1024 + lane * 16;
      const int row = b >> 7;
      const int colb = b & 127;
      gload_lds16((const char*)A + ((size_t)(m0 + row) * K + k0) * 2 + colb,
                  (char*)sA + c * 1024);
      gload_lds16((const char*)Bw + ((size_t)(n0 + row) * K + k0) * 2 + colb,
                  (char*)sB + c * 1024);
    }
    __syncthreads();
#pragma unroll
    for (int ks = 0; ks < 2; ++ks) {
      bf16x8 af[4], bf_[4];
#pragma unroll
      for (int i = 0; i < 4; ++i) {
        af[i]  = *(const bf16x8*)&sA[(wm * 64 + i * 16 + (lane & 15)) * 64 + ks * 32 + (lane >> 4) * 8];
        bf_[i] = *(const bf16x8*)&sB[(wn * 64 + i * 16 + (lane & 15)) * 64 + ks * 32 + (lane >> 4) * 8];
      }
#pragma unroll
      for (int i = 0; i < 4; ++i)
#pragma unroll
        for (int j = 0; j < 4; ++j)
          acc[i][j] = __builtin_amdgcn_mfma_f32_16x16x32_bf16(af[i], bf_[j], acc[i][j], 0, 0, 0);
    }
  }
#pragma unroll
  for (int i = 0; i < 4; ++i) {
#pragma unroll
    for (int j = 0; j < 4; ++j) {
#pragma unroll
      for (int r = 0; r < 4; ++r) {
        const int row = m0 + wm * 64 + i * 16 + (lane >> 4) * 4 + r;
        const int col = n0 + wn * 64 + j * 16 + (lane & 15);
        float v = acc[i][j][r] + bias[col];
        if (EPI == 0) {
          const int part = col >> 10, oo = col & 1023;
          const int h = oo >> 6, d = oo & 63;
          const int bb = row >> 11, s = row & 2047;
          if (part == 0)
            qo[(((size_t)bb * HH + h) * SS + s) * HDD + d] = f2bf(v * 0.18033688f); // 0.125*log2(e)
          else if (part == 1)
            ko[(((size_t)bb * HH + h) * SS + s) * HDD + d] = f2bf(v);
          else
            vo[(((size_t)bb * HH + h) * HDD + d) * SS + s] = f2bf(v);
        } else {
          co[(size_t)row * N + col] = v;
        }
      }
    }
  }
}

// Flash attention v7: swapped-operand QK^T (T12 mechanism) -> P stays in
// registers, softmax row-reduce is in-lane + 2 shfl_xor, PV A-frags are the
// lane's OWN packed p-values (any k->slot bijection is valid as long as the
// V B-frag uses the same one; V read as 2x ds_read_b64 at matching k-slots,
// conflict-free at the b64 floor). No sP. K/V double-buffered LDS
// (global_load_lds, XOR-swizzled source / swizzled read). exp2-domain
// softmax, defer-max (T13). grid (NT/2, B*H), paired q-tiles {bx, NT-1-bx}.
__global__ __launch_bounds__(256)
void attn_fwd(const short* __restrict__ Q, const short* __restrict__ K,
              const short* __restrict__ V, short* __restrict__ Y) {
  __shared__ short sK[2][64 * 64];
  __shared__ short sV[2][64 * 64];
  const int bh = blockIdx.y;
  const int tid = threadIdx.x, lane = tid & 63, w = tid >> 6;
  const size_t bqk = (size_t)bh * (SS * HDD);
  const size_t bv  = (size_t)bh * (HDD * SS);
  const int b = bh >> 4, h = bh & 15;
  const int lr = lane & 15;        // q-row index within wave's 16 rows
  const int lg = lane >> 4;        // k-group
  const int lm = lr & 7;           // swizzle row bits
  const int half4 = (lg & 1) * 4;  // b64 half (in shorts)

  // staging geometry: element e (0..511), 16B each; LDS dest linear,
  // global source slot pre-swizzled s = (e&7)^(row&7)
  const int e0 = w * 64 + lane;
  const int e1 = 256 + e0;
  const int r0 = e0 >> 3, s0 = ((e0 & 7) ^ (r0 & 7)) * 8;
  const int r1 = e1 >> 3, s1 = ((e1 & 7) ^ (r1 & 7)) * 8;

  for (int qsel = 0; qsel < 2; ++qsel) {
    const int qb = qsel ? (NT - 1 - blockIdx.x) : blockIdx.x;
    const int q0 = qb * 64;

    __syncthreads();   // protect buffer re-stage vs previous q-tile's reads

    // prologue: stage tile 0 into buffer 0
    {
      const short* gK = K + bqk;
      const short* gV = V + bv;
      gload_lds16(gK + (size_t)r0 * HDD + s0, &sK[0][e0 * 8]);
      gload_lds16(gV + (size_t)r0 * SS + s0, &sV[0][e0 * 8]);
      gload_lds16(gK + (size_t)r1 * HDD + s1, &sK[0][e1 * 8]);
      gload_lds16(gV + (size_t)r1 * SS + s1, &sV[0][e1 * 8]);
    }

    bf16x8 qf[2];
#pragma unroll
    for (int ks = 0; ks < 2; ++ks)
      qf[ks] = *(const bf16x8*)&Q[bqk + (size_t)(q0 + w * 16 + lr) * HDD + ks * 32 + lg * 8];

    f32x4 accO[4] = {};
    float m_ = -1e30f, l_ = 0.f;   // per-lane state for q-row (w*16+lr)

    int cur = 0;
    for (int kt = 0; kt <= qb; ++kt) {
      const int kc0 = kt * 64;
      __syncthreads();   // staged tile ready (vmcnt drained); prev reads done
      if (kt < qb) {     // stage next tile into the other buffer
        const short* gK = K + bqk + (size_t)(kc0 + 64) * 64;
        const short* gV = V + bv + kc0 + 64;
        gload_lds16(gK + (size_t)r0 * HDD + s0, &sK[cur ^ 1][e0 * 8]);
        gload_lds16(gV + (size_t)r0 * SS + s0, &sV[cur ^ 1][e0 * 8]);
        gload_lds16(gK + (size_t)r1 * HDD + s1, &sK[cur ^ 1][e1 * 8]);
        gload_lds16(gV + (size_t)r1 * SS + s1, &sV[cur ^ 1][e1 * 8]);
      }

      // Swapped QK^T: st = mfma(K, Q) -> st_[nf][r] = S[k=kc0+nf*16+lg*4+r][q=q0+w*16+lr]
      f32x4 st_[4] = {};
#pragma unroll
      for (int ks = 0; ks < 2; ++ks) {
#pragma unroll
        for (int nf = 0; nf < 4; ++nf) {
          const int row = nf * 16 + lr;
          const bf16x8 kf = *(const bf16x8*)&sK[cur][row * 64 + (((ks << 2) + lg) ^ lm) * 8];
          st_[nf] = __builtin_amdgcn_mfma_f32_16x16x32_bf16(kf, qf[ks], st_[nf], 0, 0, 0);
        }
      }
      if (kt == qb) {   // diagonal tile: causal mask (k > q)
        const int q = q0 + w * 16 + lr;
#pragma unroll
        for (int nf = 0; nf < 4; ++nf)
#pragma unroll
          for (int r = 0; r < 4; ++r) {
            const int k = kc0 + nf * 16 + lg * 4 + r;
            if (k > q) st_[nf][r] = -1e30f;
          }
      }

      // row max: in-lane tree over 16 + 2 cross-lane (lg replicas)
      f32x4 t01, t23;
#pragma unroll
      for (int r = 0; r < 4; ++r) {
        t01[r] = fmaxf(st_[0][r], st_[1][r]);
        t23[r] = fmaxf(st_[2][r], st_[3][r]);
      }
      float rm = -1e30f;
#pragma unroll
      for (int r = 0; r < 4; ++r) rm = fmaxf(rm, fmaxf(t01[r], t23[r]));
      rm = fmaxf(rm, __shfl_xor(rm, 16));
      rm = fmaxf(rm, __shfl_xor(rm, 32));

      // defer-max (T13): rescale only if tile max beats m_ by > 8*log2(e)
      const bool need = rm > m_ + 11.5416f;
      if (__any(need)) {
        const float mn = fmaxf(m_, rm);
        const float scale = fexp2(m_ - mn);
        m_ = mn;
        l_ *= scale;
#pragma unroll
        for (int r = 0; r < 4; ++r) {
          const float scl = __shfl(scale, (lane & 48) + (lg << 2) + r);
#pragma unroll
          for (int df = 0; df < 4; ++df) accO[df][r] *= scl;
        }
      }

      // exp2 + in-lane sum + cross-lane sum
      float rs = 0.f;
#pragma unroll
      for (int nf = 0; nf < 4; ++nf)
#pragma unroll
        for (int r = 0; r < 4; ++r) {
          const float p = fexp2(st_[nf][r] - m_);
          st_[nf][r] = p;
          rs += p;
        }
      rs += __shfl_xor(rs, 16);
      rs += __shfl_xor(rs, 32);
      l_ += rs;

      // pack P to bf16 in-register: u[nf] = {p[0..1], p[2..3]}
      unsigned u[4][2];
#pragma unroll
      for (int nf = 0; nf < 4; ++nf) {
        u[nf][0] = cvtpk(st_[nf][0], st_[nf][1]);
        u[nf][1] = cvtpk(st_[nf][2], st_[nf][3]);
      }

      // PV: call c covers k in {32c+4lg+0..3} u {32c+16+4lg+0..3} (own data);
      // V B-frag reads the same k-slots: two b64 at swizzled 16B-slots.
#pragma unroll
      for (int c = 0; c < 2; ++c) {
        int4 pw;
        pw.x = (int)u[2 * c][0];
        pw.y = (int)u[2 * c][1];
        pw.z = (int)u[2 * c + 1][0];
        pw.w = (int)u[2 * c + 1][1];
        const bf16x8 pf = __builtin_bit_cast(bf16x8, pw);
        const int p1 = ((c << 2) + (lg >> 1)) ^ lm;   // slot of k=32c+4lg
        const int p2 = p1 ^ 2;                        // slot of k=32c+16+4lg
#pragma unroll
        for (int df = 0; df < 4; ++df) {
          const int base = (df * 16 + lr) * 64;
          const int2 lo = *(const int2*)&sV[cur][base + p1 * 8 + half4];
          const int2 hi = *(const int2*)&sV[cur][base + p2 * 8 + half4];
          int4 vv;
          vv.x = lo.x; vv.y = lo.y; vv.z = hi.x; vv.w = hi.y;
          const bf16x8 vf = __builtin_bit_cast(bf16x8, vv);
          accO[df] = __builtin_amdgcn_mfma_f32_16x16x32_bf16(pf, vf, accO[df], 0, 0, 0);
        }
      }
      cur ^= 1;
    }

    // epilogue: accO row q = lg*4+r needs l_ from lane with lr' = lg*4+r
#pragma unroll
    for (int r = 0; r < 4; ++r) {
      const float lv = __shfl(l_, (lane & 48) + (lg << 2) + r);
      const float inv = frcp(lv);
      const int srow = q0 + w * 16 + lg * 4 + r;
#pragma unroll
      for (int df = 0; df < 4; ++df) {
        const int dcol = h * HDD + df * 16 + lr;
        Y[((size_t)b * SS + srow) * DD + dcol] = f2bf(accO[df][r] * inv);
      }
    }
  }
}

extern "C" void kernel_launch(void* const* d_in, const int* in_sizes, int n_in,
                              void* d_out, int out_size, void* d_ws, size_t ws_size,
                              hipStream_t stream) {
  const float* x     = (const float*)d_in[0];
  const float* w_qkv = (const float*)d_in[1];
  const float* b_qkv = (const float*)d_in[2];
  const float* w_out = (const float*)d_in[3];
  const float* b_out = (const float*)d_in[4];
  float* out = (float*)d_out;

  const size_t nx = (size_t)MM * DD;        // 8388608
  const size_t nwq = (size_t)3 * DD * DD;   // 3145728
  const size_t nwo = (size_t)DD * DD;       // 1048576

  short* x_bf    = (short*)d_ws;
  short* wqkv_bf = x_bf + nx;
  short* wout_bf = wqkv_bf + nwq;
  short* q_ws    = wout_bf + nwo;
  short* k_ws    = q_ws + nx;
  short* v_ws    = k_ws + nx;
  short* y_ws    = v_ws + nx;

  cast_f32_bf16<<<dim3(2048), dim3(256), 0, stream>>>(x, (unsigned long long*)x_bf, (int)(nx / 4));
  cast_f32_bf16<<<dim3(1024), dim3(256), 0, stream>>>(w_qkv, (unsigned long long*)wqkv_bf, (int)(nwq / 4));
  cast_f32_bf16<<<dim3(512), dim3(256), 0, stream>>>(w_out, (unsigned long long*)wout_bf, (int)(nwo / 4));

  gemm_bt<0><<<dim3(3 * DD / 128, MM / 128), dim3(256), 0, stream>>>(
      x_bf, wqkv_bf, b_qkv, q_ws, k_ws, v_ws, nullptr, MM, 3 * DD, DD);

  attn_fwd<<<dim3(NT / 2, BB * HH), dim3(256), 0, stream>>>(q_ws, k_ws, v_ws, y_ws);

  gemm_bt<1><<<dim3(DD / 128, MM / 128), dim3(256), 0, stream>>>(
      y_ws, wout_bf, b_out, nullptr, nullptr, nullptr, out, MM, DD, DD);
}

// Round 8
// 222.054 us; speedup vs baseline: 1.2215x; 1.0352x over previous
//
#include <hip/hip_runtime.h>
#include <hip/hip_bf16.h>

#define DEV __device__ __forceinline__

typedef __attribute__((ext_vector_type(8))) short bf16x8;
typedef __attribute__((ext_vector_type(4))) float f32x4;

// Problem constants
#define BB 4
#define SS 2048
#define DD 1024
#define HH 16
#define HDD 64
#define MM (BB * SS)   // 8192
#define NT (SS / 64)   // 32 q-tiles per (b,h)

DEV short f2bf(float f) {
  unsigned u = __builtin_bit_cast(unsigned, f);
  u = u + 0x7fffu + ((u >> 16) & 1u);
  return (short)(u >> 16);
}

DEV float fexp2(float x) {  // raw v_exp_f32 (2^x)
  float r;
  asm("v_exp_f32 %0, %1" : "=v"(r) : "v"(x));
  return r;
}
DEV float frcp(float x) {
  float r;
  asm("v_rcp_f32 %0, %1" : "=v"(r) : "v"(x));
  return r;
}
DEV unsigned cvtpk(float a, float b) {  // {lo:bf16(a), hi:bf16(b)}
  unsigned r;
  asm("v_cvt_pk_bf16_f32 %0, %1, %2" : "=v"(r) : "v"(a), "v"(b));
  return r;
}

DEV void gload_lds16(const void* g, void* l) {
  __builtin_amdgcn_global_load_lds((const __attribute__((address_space(1))) void*)g,
                                   (__attribute__((address_space(3))) void*)l, 16, 0, 0);
}

DEV void cast_range(const float* __restrict__ in, unsigned long long* __restrict__ out,
                    int n4, int start, int stride) {
  for (int i = start; i < n4; i += stride) {
    const float4 f = ((const float4*)in)[i];
    unsigned long long a = (unsigned long long)(unsigned short)f2bf(f.x)
        | ((unsigned long long)(unsigned short)f2bf(f.y) << 16)
        | ((unsigned long long)(unsigned short)f2bf(f.z) << 32)
        | ((unsigned long long)(unsigned short)f2bf(f.w) << 48);
    out[i] = a;
  }
}

// One launch, three buffers (x, w_qkv, w_out)
__global__ __launch_bounds__(256)
void cast3_f32_bf16(const float* __restrict__ x, unsigned long long* __restrict__ ox, int nx4,
                    const float* __restrict__ wq, unsigned long long* __restrict__ owq, int nwq4,
                    const float* __restrict__ wo, unsigned long long* __restrict__ owo, int nwo4) {
  const int start = blockIdx.x * 256 + threadIdx.x;
  const int stride = gridDim.x * 256;
  cast_range(x, ox, nx4, start, stride);
  cast_range(wq, owq, nwq4, start, stride);
  cast_range(wo, owo, nwo4, start, stride);
}

// C = A[M,K] * Bw[N,K]^T + bias.  EPI=0: scatter to Q/K/V bf16 ws. EPI=1: f32 out.
// Q pre-scaled by (1/sqrt(HD))*log2(e): attention softmax runs in exp2 domain.
// V stored with per-64 quad permutation tau (q&8 | (q&3)<<1 | (q>>2)&1) so the
// attention PV B-fragment is one contiguous b128 in LDS (quads g and g+4 adjacent).
template<int EPI>
__global__ __launch_bounds__(256)
void gemm_bt(const short* __restrict__ A, const short* __restrict__ Bw,
             const float* __restrict__ bias,
             short* __restrict__ qo, short* __restrict__ ko, short* __restrict__ vo,
             float* __restrict__ co,
             int M, int N, int K) {
  __shared__ short sA[128 * 64];
  __shared__ short sB[128 * 64];
  const int lane = threadIdx.x & 63;
  const int wv = threadIdx.x >> 6;
  const int wm = wv >> 1, wn = wv & 1;
  const int m0 = blockIdx.y * 128;
  const int n0 = blockIdx.x * 128;
  f32x4 acc[4][4] = {};
  const int nkt = K >> 6;
  for (int kt = 0; kt < nkt; ++kt) {
    const int k0 = kt << 6;
    if (kt) __syncthreads();
#pragma unroll
    for (int i = 0; i < 4; ++i) {
      const int c = i * 4 + wv;
      const int b = c * 1024 + lane * 16;
      const int row = b >> 7;
      const int colb = b & 127;
      gload_lds16((const char*)A + ((size_t)(m0 + row) * K + k0) * 2 + colb,
                  (char*)sA + c * 1024);
      gload_lds16((const char*)Bw + ((size_t)(n0 + row) * K + k0) * 2 + colb,
                  (char*)sB + c * 1024);
    }
    __syncthreads();
#pragma unroll
    for (int ks = 0; ks < 2; ++ks) {
      bf16x8 af[4], bf_[4];
#pragma unroll
      for (int i = 0; i < 4; ++i) {
        af[i]  = *(const bf16x8*)&sA[(wm * 64 + i * 16 + (lane & 15)) * 64 + ks * 32 + (lane >> 4) * 8];
        bf_[i] = *(const bf16x8*)&sB[(wn * 64 + i * 16 + (lane & 15)) * 64 + ks * 32 + (lane >> 4) * 8];
      }
#pragma unroll
      for (int i = 0; i < 4; ++i)
#pragma unroll
        for (int j = 0; j < 4; ++j)
          acc[i][j] = __builtin_amdgcn_mfma_f32_16x16x32_bf16(af[i], bf_[j], acc[i][j], 0, 0, 0);
    }
  }
#pragma unroll
  for (int i = 0; i < 4; ++i) {
#pragma unroll
    for (int j = 0; j < 4; ++j) {
#pragma unroll
      for (int r = 0; r < 4; ++r) {
        const int row = m0 + wm * 64 + i * 16 + (lane >> 4) * 4 + r;
        const int col = n0 + wn * 64 + j * 16 + (lane & 15);
        float v = acc[i][j][r] + bias[col];
        if (EPI == 0) {
          const int part = col >> 10, oo = col & 1023;
          const int h = oo >> 6, d = oo & 63;
          const int bb = row >> 11, s = row & 2047;
          if (part == 0)
            qo[(((size_t)bb * HH + h) * SS + s) * HDD + d] = f2bf(v * 0.18033688f); // 0.125*log2(e)
          else if (part == 1)
            ko[(((size_t)bb * HH + h) * SS + s) * HDD + d] = f2bf(v);
          else {
            const int q = (s >> 2) & 15;
            const int tau = (q & 8) | ((q & 3) << 1) | ((q >> 2) & 1);
            vo[(((size_t)bb * HH + h) * HDD + d) * SS + (s & ~63) + (tau << 2) + (s & 3)] = f2bf(v);
          }
        } else {
          co[(size_t)row * N + col] = v;
        }
      }
    }
  }
}

// Flash attention v8: swapped-operand QK^T -> P stays in registers; softmax
// row-reduce in-lane + 2 shfl_xor; PV A-frag = lane's own packed p-values.
// V global layout tau-interleaved so the matching V B-frag is ONE b128 at the
// XOR-swizzled slot ((c<<2)+lg)^lm (same conflict-free pattern as K reads).
// K/V double-buffered LDS via global_load_lds (XOR-swizzled source / swizzled
// read, rule #21). exp2-domain softmax, defer-max (T13). grid (NT/2, B*H),
// paired q-tiles {bx, NT-1-bx} -> uniform 33 tiles/block.
__global__ __launch_bounds__(256)
void attn_fwd(const short* __restrict__ Q, const short* __restrict__ K,
              const short* __restrict__ V, short* __restrict__ Y) {
  __shared__ short sK[2][64 * 64];
  __shared__ short sV[2][64 * 64];
  const int bh = blockIdx.y;
  const int tid = threadIdx.x, lane = tid & 63, w = tid >> 6;
  const size_t bqk = (size_t)bh * (SS * HDD);
  const size_t bv  = (size_t)bh * (HDD * SS);
  const int b = bh >> 4, h = bh & 15;
  const int lr = lane & 15;        // q-row index within wave's 16 rows
  const int lg = lane >> 4;        // k-group
  const int lm = lr & 7;           // swizzle row bits

  // staging geometry: element e (0..511), 16B each; LDS dest linear,
  // global source slot pre-swizzled s = (e&7)^(row&7)
  const int e0 = w * 64 + lane;
  const int e1 = 256 + e0;
  const int r0 = e0 >> 3, s0 = ((e0 & 7) ^ (r0 & 7)) * 8;
  const int r1 = e1 >> 3, s1 = ((e1 & 7) ^ (r1 & 7)) * 8;

  for (int qsel = 0; qsel < 2; ++qsel) {
    const int qb = qsel ? (NT - 1 - blockIdx.x) : blockIdx.x;
    const int q0 = qb * 64;

    __syncthreads();   // protect buffer re-stage vs previous q-tile's reads

    // prologue: stage tile 0 into buffer 0
    {
      const short* gK = K + bqk;
      const short* gV = V + bv;
      gload_lds16(gK + (size_t)r0 * HDD + s0, &sK[0][e0 * 8]);
      gload_lds16(gV + (size_t)r0 * SS + s0, &sV[0][e0 * 8]);
      gload_lds16(gK + (size_t)r1 * HDD + s1, &sK[0][e1 * 8]);
      gload_lds16(gV + (size_t)r1 * SS + s1, &sV[0][e1 * 8]);
    }

    bf16x8 qf[2];
#pragma unroll
    for (int ks = 0; ks < 2; ++ks)
      qf[ks] = *(const bf16x8*)&Q[bqk + (size_t)(q0 + w * 16 + lr) * HDD + ks * 32 + lg * 8];

    f32x4 accO[4] = {};
    float m_ = -1e30f, l_ = 0.f;   // per-lane state for q-row (w*16+lr)

    int cur = 0;
    for (int kt = 0; kt <= qb; ++kt) {
      const int kc0 = kt * 64;
      __syncthreads();   // staged tile ready (vmcnt drained); prev reads done
      if (kt < qb) {     // stage next tile into the other buffer
        const short* gK = K + bqk + (size_t)(kc0 + 64) * 64;
        const short* gV = V + bv + kc0 + 64;
        gload_lds16(gK + (size_t)r0 * HDD + s0, &sK[cur ^ 1][e0 * 8]);
        gload_lds16(gV + (size_t)r0 * SS + s0, &sV[cur ^ 1][e0 * 8]);
        gload_lds16(gK + (size_t)r1 * HDD + s1, &sK[cur ^ 1][e1 * 8]);
        gload_lds16(gV + (size_t)r1 * SS + s1, &sV[cur ^ 1][e1 * 8]);
      }

      // Swapped QK^T: st = mfma(K, Q) -> st_[nf][r] = S[k=kc0+nf*16+lg*4+r][q=q0+w*16+lr]
      f32x4 st_[4] = {};
#pragma unroll
      for (int ks = 0; ks < 2; ++ks) {
#pragma unroll
        for (int nf = 0; nf < 4; ++nf) {
          const int row = nf * 16 + lr;
          const bf16x8 kf = *(const bf16x8*)&sK[cur][row * 64 + (((ks << 2) + lg) ^ lm) * 8];
          st_[nf] = __builtin_amdgcn_mfma_f32_16x16x32_bf16(kf, qf[ks], st_[nf], 0, 0, 0);
        }
      }
      if (kt == qb) {   // diagonal tile: causal mask (k > q)
        const int q = q0 + w * 16 + lr;
#pragma unroll
        for (int nf = 0; nf < 4; ++nf)
#pragma unroll
          for (int r = 0; r < 4; ++r) {
            const int k = kc0 + nf * 16 + lg * 4 + r;
            if (k > q) st_[nf][r] = -1e30f;
          }
      }

      // row max: in-lane tree over 16 + 2 cross-lane (lg replicas)
      f32x4 t01, t23;
#pragma unroll
      for (int r = 0; r < 4; ++r) {
        t01[r] = fmaxf(st_[0][r], st_[1][r]);
        t23[r] = fmaxf(st_[2][r], st_[3][r]);
      }
      float rm = -1e30f;
#pragma unroll
      for (int r = 0; r < 4; ++r) rm = fmaxf(rm, fmaxf(t01[r], t23[r]));
      rm = fmaxf(rm, __shfl_xor(rm, 16));
      rm = fmaxf(rm, __shfl_xor(rm, 32));

      // defer-max (T13): rescale only if tile max beats m_ by > 8*log2(e)
      const bool need = rm > m_ + 11.5416f;
      if (__any(need)) {
        const float mn = fmaxf(m_, rm);
        const float scale = fexp2(m_ - mn);
        m_ = mn;
        l_ *= scale;
#pragma unroll
        for (int r = 0; r < 4; ++r) {
          const float scl = __shfl(scale, (lane & 48) + (lg << 2) + r);
#pragma unroll
          for (int df = 0; df < 4; ++df) accO[df][r] *= scl;
        }
      }

      // exp2 + in-lane sum + cross-lane sum
      float rs = 0.f;
#pragma unroll
      for (int nf = 0; nf < 4; ++nf)
#pragma unroll
        for (int r = 0; r < 4; ++r) {
          const float p = fexp2(st_[nf][r] - m_);
          st_[nf][r] = p;
          rs += p;
        }
      rs += __shfl_xor(rs, 16);
      rs += __shfl_xor(rs, 32);
      l_ += rs;

      // pack P to bf16 in-register: u[nf] = {p[0..1], p[2..3]}
      unsigned u[4][2];
#pragma unroll
      for (int nf = 0; nf < 4; ++nf) {
        u[nf][0] = cvtpk(st_[nf][0], st_[nf][1]);
        u[nf][1] = cvtpk(st_[nf][2], st_[nf][3]);
      }

      // PV: call c covers k = 32c+4lg+{0..3} u 32c+16+4lg+{0..3} (lane's own
      // p-values); V B-frag = single b128 at tau-interleaved swizzled slot.
#pragma unroll
      for (int c = 0; c < 2; ++c) {
        int4 pw;
        pw.x = (int)u[2 * c][0];
        pw.y = (int)u[2 * c][1];
        pw.z = (int)u[2 * c + 1][0];
        pw.w = (int)u[2 * c + 1][1];
        const bf16x8 pf = __builtin_bit_cast(bf16x8, pw);
        const int slot = (((c << 2) + lg) ^ lm) * 8;
#pragma unroll
        for (int df = 0; df < 4; ++df) {
          const bf16x8 vf = *(const bf16x8*)&sV[cur][(df * 16 + lr) * 64 + slot];
          accO[df] = __builtin_amdgcn_mfma_f32_16x16x32_bf16(pf, vf, accO[df], 0, 0, 0);
        }
      }
      cur ^= 1;
    }

    // epilogue: accO row q = lg*4+r needs l_ from lane with lr' = lg*4+r
#pragma unroll
    for (int r = 0; r < 4; ++r) {
      const float lv = __shfl(l_, (lane & 48) + (lg << 2) + r);
      const float inv = frcp(lv);
      const int srow = q0 + w * 16 + lg * 4 + r;
#pragma unroll
      for (int df = 0; df < 4; ++df) {
        const int dcol = h * HDD + df * 16 + lr;
        Y[((size_t)b * SS + srow) * DD + dcol] = f2bf(accO[df][r] * inv);
      }
    }
  }
}

extern "C" void kernel_launch(void* const* d_in, const int* in_sizes, int n_in,
                              void* d_out, int out_size, void* d_ws, size_t ws_size,
                              hipStream_t stream) {
  const float* x     = (const float*)d_in[0];
  const float* w_qkv = (const float*)d_in[1];
  const float* b_qkv = (const float*)d_in[2];
  const float* w_out = (const float*)d_in[3];
  const float* b_out = (const float*)d_in[4];
  float* out = (float*)d_out;

  const size_t nx = (size_t)MM * DD;        // 8388608
  const size_t nwq = (size_t)3 * DD * DD;   // 3145728
  const size_t nwo = (size_t)DD * DD;       // 1048576

  short* x_bf    = (short*)d_ws;
  short* wqkv_bf = x_bf + nx;
  short* wout_bf = wqkv_bf + nwq;
  short* q_ws    = wout_bf + nwo;
  short* k_ws    = q_ws + nx;
  short* v_ws    = k_ws + nx;
  short* y_ws    = v_ws + nx;

  cast3_f32_bf16<<<dim3(2048), dim3(256), 0, stream>>>(
      x, (unsigned long long*)x_bf, (int)(nx / 4),
      w_qkv, (unsigned long long*)wqkv_bf, (int)(nwq / 4),
      w_out, (unsigned long long*)wout_bf, (int)(nwo / 4));

  gemm_bt<0><<<dim3(3 * DD / 128, MM / 128), dim3(256), 0, stream>>>(
      x_bf, wqkv_bf, b_qkv, q_ws, k_ws, v_ws, nullptr, MM, 3 * DD, DD);

  attn_fwd<<<dim3(NT / 2, BB * HH), dim3(256), 0, stream>>>(q_ws, k_ws, v_ws, y_ws);

  gemm_bt<1><<<dim3(DD / 128, MM / 128), dim3(256), 0, stream>>>(
      y_ws, wout_bf, b_out, nullptr, nullptr, nullptr, out, MM, DD, DD);
}

// Round 9
// 200.587 us; speedup vs baseline: 1.3522x; 1.1070x over previous
//
#include <hip/hip_runtime.h>
#include <hip/hip_bf16.h>

#define DEV __device__ __forceinline__

typedef __attribute__((ext_vector_type(8))) short bf16x8;
typedef __attribute__((ext_vector_type(4))) float f32x4;

// Problem constants
#define BB 4
#define SS 2048
#define DD 1024
#define HH 16
#define HDD 64
#define MM (BB * SS)   // 8192
#define NT (SS / 64)   // 32 kv-tiles per (b,h)
#define NQT (SS / 128) // 16 q-tiles of 128 rows

DEV short f2bf(float f) {
  unsigned u = __builtin_bit_cast(unsigned, f);
  u = u + 0x7fffu + ((u >> 16) & 1u);
  return (short)(u >> 16);
}

DEV float fexp2(float x) {  // raw v_exp_f32 (2^x)
  float r;
  asm("v_exp_f32 %0, %1" : "=v"(r) : "v"(x));
  return r;
}
DEV float frcp(float x) {
  float r;
  asm("v_rcp_f32 %0, %1" : "=v"(r) : "v"(x));
  return r;
}
DEV unsigned cvtpk(float a, float b) {  // {lo:bf16(a), hi:bf16(b)}
  unsigned r;
  asm("v_cvt_pk_bf16_f32 %0, %1, %2" : "=v"(r) : "v"(a), "v"(b));
  return r;
}

DEV void gload_lds16(const void* g, void* l) {
  __builtin_amdgcn_global_load_lds((const __attribute__((address_space(1))) void*)g,
                                   (__attribute__((address_space(3))) void*)l, 16, 0, 0);
}

DEV void cast_range(const float* __restrict__ in, unsigned long long* __restrict__ out,
                    int n4, int start, int stride) {
  for (int i = start; i < n4; i += stride) {
    const float4 f = ((const float4*)in)[i];
    unsigned long long a = (unsigned long long)(unsigned short)f2bf(f.x)
        | ((unsigned long long)(unsigned short)f2bf(f.y) << 16)
        | ((unsigned long long)(unsigned short)f2bf(f.z) << 32)
        | ((unsigned long long)(unsigned short)f2bf(f.w) << 48);
    out[i] = a;
  }
}

// One launch, three buffers (x, w_qkv, w_out)
__global__ __launch_bounds__(256)
void cast3_f32_bf16(const float* __restrict__ x, unsigned long long* __restrict__ ox, int nx4,
                    const float* __restrict__ wq, unsigned long long* __restrict__ owq, int nwq4,
                    const float* __restrict__ wo, unsigned long long* __restrict__ owo, int nwo4) {
  const int start = blockIdx.x * 256 + threadIdx.x;
  const int stride = gridDim.x * 256;
  cast_range(x, ox, nx4, start, stride);
  cast_range(wq, owq, nwq4, start, stride);
  cast_range(wo, owo, nwo4, start, stride);
}

// C = A[M,K] * Bw[N,K]^T + bias.  EPI=0: scatter to Q/K/V bf16 ws. EPI=1: f32 out.
// Q pre-scaled by (1/sqrt(HD))*log2(e): attention softmax runs in exp2 domain.
// V stored with per-64 quad permutation tau (q&8 | (q&3)<<1 | (q>>2)&1) so the
// attention PV B-fragment is one contiguous b128 in LDS (quads g and g+4 adjacent).
template<int EPI>
__global__ __launch_bounds__(256)
void gemm_bt(const short* __restrict__ A, const short* __restrict__ Bw,
             const float* __restrict__ bias,
             short* __restrict__ qo, short* __restrict__ ko, short* __restrict__ vo,
             float* __restrict__ co,
             int M, int N, int K) {
  __shared__ short sA[128 * 64];
  __shared__ short sB[128 * 64];
  const int lane = threadIdx.x & 63;
  const int wv = threadIdx.x >> 6;
  const int wm = wv >> 1, wn = wv & 1;
  const int m0 = blockIdx.y * 128;
  const int n0 = blockIdx.x * 128;
  f32x4 acc[4][4] = {};
  const int nkt = K >> 6;
  for (int kt = 0; kt < nkt; ++kt) {
    const int k0 = kt << 6;
    if (kt) __syncthreads();
#pragma unroll
    for (int i = 0; i < 4; ++i) {
      const int c = i * 4 + wv;
      const int b = c * 1024 + lane * 16;
      const int row = b >> 7;
      const int colb = b & 127;
      gload_lds16((const char*)A + ((size_t)(m0 + row) * K + k0) * 2 + colb,
                  (char*)sA + c * 1024);
      gload_lds16((const char*)Bw + ((size_t)(n0 + row) * K + k0) * 2 + colb,
                  (char*)sB + c * 1024);
    }
    __syncthreads();
#pragma unroll
    for (int ks = 0; ks < 2; ++ks) {
      bf16x8 af[4], bf_[4];
#pragma unroll
      for (int i = 0; i < 4; ++i) {
        af[i]  = *(const bf16x8*)&sA[(wm * 64 + i * 16 + (lane & 15)) * 64 + ks * 32 + (lane >> 4) * 8];
        bf_[i] = *(const bf16x8*)&sB[(wn * 64 + i * 16 + (lane & 15)) * 64 + ks * 32 + (lane >> 4) * 8];
      }
#pragma unroll
      for (int i = 0; i < 4; ++i)
#pragma unroll
        for (int j = 0; j < 4; ++j)
          acc[i][j] = __builtin_amdgcn_mfma_f32_16x16x32_bf16(af[i], bf_[j], acc[i][j], 0, 0, 0);
    }
  }
#pragma unroll
  for (int i = 0; i < 4; ++i) {
#pragma unroll
    for (int j = 0; j < 4; ++j) {
#pragma unroll
      for (int r = 0; r < 4; ++r) {
        const int row = m0 + wm * 64 + i * 16 + (lane >> 4) * 4 + r;
        const int col = n0 + wn * 64 + j * 16 + (lane & 15);
        float v = acc[i][j][r] + bias[col];
        if (EPI == 0) {
          const int part = col >> 10, oo = col & 1023;
          const int h = oo >> 6, d = oo & 63;
          const int bb = row >> 11, s = row & 2047;
          if (part == 0)
            qo[(((size_t)bb * HH + h) * SS + s) * HDD + d] = f2bf(v * 0.18033688f); // 0.125*log2(e)
          else if (part == 1)
            ko[(((size_t)bb * HH + h) * SS + s) * HDD + d] = f2bf(v);
          else {
            const int q = (s >> 2) & 15;
            const int tau = (q & 8) | ((q & 3) << 1) | ((q >> 2) & 1);
            vo[(((size_t)bb * HH + h) * HDD + d) * SS + (s & ~63) + (tau << 2) + (s & 3)] = f2bf(v);
          }
        } else {
          co[(size_t)row * N + col] = v;
        }
      }
    }
  }
}

// Flash attention v9: QBLK=128 (4 waves x 32 q-rows, two 16-row groups per
// wave) to amortize per-tile fixed costs: K-frag reads feed 2 MFMAs each,
// V reads shared across both q-groups, barriers/staging per 2x work.
// Swapped-operand QK^T; P stays in registers; PV B-frag = one b128 via the
// tau-interleaved V global layout. K/V double-buffered LDS (global_load_lds,
// XOR-swizzled source / swizzled read). exp2 softmax, defer-max (T13).
// grid (NQT/2, B*H): paired q-tiles {bx, NQT-1-bx} -> uniform 34 kv-tiles.
__global__ __launch_bounds__(256)
void attn_fwd(const short* __restrict__ Q, const short* __restrict__ K,
              const short* __restrict__ V, short* __restrict__ Y) {
  __shared__ short sK[2][64 * 64];
  __shared__ short sV[2][64 * 64];
  const int bh = blockIdx.y;
  const int tid = threadIdx.x, lane = tid & 63, w = tid >> 6;
  const size_t bqk = (size_t)bh * (SS * HDD);
  const size_t bv  = (size_t)bh * (HDD * SS);
  const int b = bh >> 4, h = bh & 15;
  const int lr = lane & 15;        // q-col index within 16-group
  const int lg = lane >> 4;        // k-group
  const int lm = lr & 7;           // swizzle row bits

  // staging geometry: element e (0..511), 16B each; LDS dest linear,
  // global source slot pre-swizzled s = (e&7)^(row&7)
  const int e0 = w * 64 + lane;
  const int e1 = 256 + e0;
  const int r0 = e0 >> 3, s0 = ((e0 & 7) ^ (r0 & 7)) * 8;
  const int r1 = e1 >> 3, s1 = ((e1 & 7) ^ (r1 & 7)) * 8;

  for (int qsel = 0; qsel < 2; ++qsel) {
    const int qt = qsel ? (NQT - 1 - blockIdx.x) : blockIdx.x;
    const int q0 = qt * 128;
    const int nkv = 2 * qt + 2;

    __syncthreads();   // protect buffer re-stage vs previous q-tile's reads

    // prologue: stage kv-tile 0 into buffer 0
    {
      const short* gK = K + bqk;
      const short* gV = V + bv;
      gload_lds16(gK + (size_t)r0 * HDD + s0, &sK[0][e0 * 8]);
      gload_lds16(gV + (size_t)r0 * SS + s0, &sV[0][e0 * 8]);
      gload_lds16(gK + (size_t)r1 * HDD + s1, &sK[0][e1 * 8]);
      gload_lds16(gV + (size_t)r1 * SS + s1, &sV[0][e1 * 8]);
    }

    // per-wave 32 q-rows: qbase + g*16 + lr
    const int qbase = q0 + w * 32;
    bf16x8 qf[2][2];
#pragma unroll
    for (int g = 0; g < 2; ++g)
#pragma unroll
      for (int ks = 0; ks < 2; ++ks)
        qf[g][ks] = *(const bf16x8*)&Q[bqk + (size_t)(qbase + g * 16 + lr) * HDD + ks * 32 + lg * 8];

    f32x4 accO[2][4] = {};
    float m_[2] = {-1e30f, -1e30f}, l_[2] = {0.f, 0.f};

    int cur = 0;
    for (int kt = 0; kt < nkv; ++kt) {
      const int kc0 = kt * 64;
      __syncthreads();   // staged tile ready (vmcnt drained); prev reads done
      if (kt < nkv - 1) {   // stage next kv-tile into the other buffer
        const short* gK = K + bqk + (size_t)(kc0 + 64) * 64;
        const short* gV = V + bv + kc0 + 64;
        gload_lds16(gK + (size_t)r0 * HDD + s0, &sK[cur ^ 1][e0 * 8]);
        gload_lds16(gV + (size_t)r0 * SS + s0, &sV[cur ^ 1][e0 * 8]);
        gload_lds16(gK + (size_t)r1 * HDD + s1, &sK[cur ^ 1][e1 * 8]);
        gload_lds16(gV + (size_t)r1 * SS + s1, &sV[cur ^ 1][e1 * 8]);
      }

      // Swapped QK^T, both q-groups share each K fragment:
      // st[g][nf][r] = S[k=kc0+nf*16+lg*4+r][q=qbase+g*16+lr]
      f32x4 st[2][4] = {};
#pragma unroll
      for (int ks = 0; ks < 2; ++ks) {
#pragma unroll
        for (int nf = 0; nf < 4; ++nf) {
          const int row = nf * 16 + lr;
          const bf16x8 kf = *(const bf16x8*)&sK[cur][row * 64 + (((ks << 2) + lg) ^ lm) * 8];
          st[0][nf] = __builtin_amdgcn_mfma_f32_16x16x32_bf16(kf, qf[0][ks], st[0][nf], 0, 0, 0);
          st[1][nf] = __builtin_amdgcn_mfma_f32_16x16x32_bf16(kf, qf[1][ks], st[1][nf], 0, 0, 0);
        }
      }
      if (kt >= nkv - 2) {   // diagonal tiles: causal mask (k > q)
#pragma unroll
        for (int g = 0; g < 2; ++g) {
          const int q = qbase + g * 16 + lr;
#pragma unroll
          for (int nf = 0; nf < 4; ++nf)
#pragma unroll
            for (int r = 0; r < 4; ++r) {
              const int k = kc0 + nf * 16 + lg * 4 + r;
              if (k > q) st[g][nf][r] = -1e30f;
            }
        }
      }

      unsigned u[2][4][2];
#pragma unroll
      for (int g = 0; g < 2; ++g) {
        // row max: in-lane tree over 16 + 2 cross-lane (lg replicas)
        float rm = -1e30f;
#pragma unroll
        for (int r = 0; r < 4; ++r)
          rm = fmaxf(rm, fmaxf(fmaxf(st[g][0][r], st[g][1][r]), fmaxf(st[g][2][r], st[g][3][r])));
        rm = fmaxf(rm, __shfl_xor(rm, 16));
        rm = fmaxf(rm, __shfl_xor(rm, 32));

        // defer-max (T13): rescale only if tile max beats m_ by > 8*log2(e)
        const bool need = rm > m_[g] + 11.5416f;
        if (__any(need)) {
          const float mn = fmaxf(m_[g], rm);
          const float scale = fexp2(m_[g] - mn);
          m_[g] = mn;
          l_[g] *= scale;
#pragma unroll
          for (int r = 0; r < 4; ++r) {
            const float scl = __shfl(scale, (lane & 48) + (lg << 2) + r);
#pragma unroll
            for (int df = 0; df < 4; ++df) accO[g][df][r] *= scl;
          }
        }

        // exp2 + in-lane sum + cross-lane sum
        float rs = 0.f;
#pragma unroll
        for (int nf = 0; nf < 4; ++nf)
#pragma unroll
          for (int r = 0; r < 4; ++r) {
            const float p = fexp2(st[g][nf][r] - m_[g]);
            st[g][nf][r] = p;
            rs += p;
          }
        rs += __shfl_xor(rs, 16);
        rs += __shfl_xor(rs, 32);
        l_[g] += rs;

        // pack P to bf16 in-register
#pragma unroll
        for (int nf = 0; nf < 4; ++nf) {
          u[g][nf][0] = cvtpk(st[g][nf][0], st[g][nf][1]);
          u[g][nf][1] = cvtpk(st[g][nf][2], st[g][nf][3]);
        }
      }

      // PV: call c covers k = 32c+4lg+{0..3} u 32c+16+4lg+{0..3}; V B-frag =
      // single b128 at tau-interleaved swizzled slot, shared by both q-groups.
#pragma unroll
      for (int c = 0; c < 2; ++c) {
        int4 pw0, pw1;
        pw0.x = (int)u[0][2 * c][0]; pw0.y = (int)u[0][2 * c][1];
        pw0.z = (int)u[0][2 * c + 1][0]; pw0.w = (int)u[0][2 * c + 1][1];
        pw1.x = (int)u[1][2 * c][0]; pw1.y = (int)u[1][2 * c][1];
        pw1.z = (int)u[1][2 * c + 1][0]; pw1.w = (int)u[1][2 * c + 1][1];
        const bf16x8 pf0 = __builtin_bit_cast(bf16x8, pw0);
        const bf16x8 pf1 = __builtin_bit_cast(bf16x8, pw1);
        const int slot = (((c << 2) + lg) ^ lm) * 8;
#pragma unroll
        for (int df = 0; df < 4; ++df) {
          const bf16x8 vf = *(const bf16x8*)&sV[cur][(df * 16 + lr) * 64 + slot];
          accO[0][df] = __builtin_amdgcn_mfma_f32_16x16x32_bf16(pf0, vf, accO[0][df], 0, 0, 0);
          accO[1][df] = __builtin_amdgcn_mfma_f32_16x16x32_bf16(pf1, vf, accO[1][df], 0, 0, 0);
        }
      }
      cur ^= 1;
    }

    // epilogue: accO[g] row q = lg*4+r needs l_ from lane with lr' = lg*4+r
#pragma unroll
    for (int g = 0; g < 2; ++g)
#pragma unroll
      for (int r = 0; r < 4; ++r) {
        const float lv = __shfl(l_[g], (lane & 48) + (lg << 2) + r);
        const float inv = frcp(lv);
        const int srow = qbase + g * 16 + lg * 4 + r;
#pragma unroll
        for (int df = 0; df < 4; ++df) {
          const int dcol = h * HDD + df * 16 + lr;
          Y[((size_t)b * SS + srow) * DD + dcol] = f2bf(accO[g][df][r] * inv);
        }
      }
  }
}

extern "C" void kernel_launch(void* const* d_in, const int* in_sizes, int n_in,
                              void* d_out, int out_size, void* d_ws, size_t ws_size,
                              hipStream_t stream) {
  const float* x     = (const float*)d_in[0];
  const float* w_qkv = (const float*)d_in[1];
  const float* b_qkv = (const float*)d_in[2];
  const float* w_out = (const float*)d_in[3];
  const float* b_out = (const float*)d_in[4];
  float* out = (float*)d_out;

  const size_t nx = (size_t)MM * DD;        // 8388608
  const size_t nwq = (size_t)3 * DD * DD;   // 3145728
  const size_t nwo = (size_t)DD * DD;       // 1048576

  short* x_bf    = (short*)d_ws;
  short* wqkv_bf = x_bf + nx;
  short* wout_bf = wqkv_bf + nwq;
  short* q_ws    = wout_bf + nwo;
  short* k_ws    = q_ws + nx;
  short* v_ws    = k_ws + nx;
  short* y_ws    = v_ws + nx;

  cast3_f32_bf16<<<dim3(2048), dim3(256), 0, stream>>>(
      x, (unsigned long long*)x_bf, (int)(nx / 4),
      w_qkv, (unsigned long long*)wqkv_bf, (int)(nwq / 4),
      w_out, (unsigned long long*)wout_bf, (int)(nwo / 4));

  gemm_bt<0><<<dim3(3 * DD / 128, MM / 128), dim3(256), 0, stream>>>(
      x_bf, wqkv_bf, b_qkv, q_ws, k_ws, v_ws, nullptr, MM, 3 * DD, DD);

  attn_fwd<<<dim3(NQT / 2, BB * HH), dim3(256), 0, stream>>>(q_ws, k_ws, v_ws, y_ws);

  gemm_bt<1><<<dim3(DD / 128, MM / 128), dim3(256), 0, stream>>>(
      y_ws, wout_bf, b_out, nullptr, nullptr, nullptr, out, MM, DD, DD);
}

// Round 10
// 198.156 us; speedup vs baseline: 1.3688x; 1.0123x over previous
//
#include <hip/hip_runtime.h>
#include <hip/hip_bf16.h>

#define DEV __device__ __forceinline__

typedef __attribute__((ext_vector_type(8))) short bf16x8;
typedef __attribute__((ext_vector_type(4))) float f32x4;

// Problem constants
#define BB 4
#define SS 2048
#define DD 1024
#define HH 16
#define HDD 64
#define MM (BB * SS)   // 8192
#define NT (SS / 64)   // 32 kv-tiles per (b,h)
#define NQT (SS / 128) // 16 q-tiles of 128 rows

DEV short f2bf(float f) {
  unsigned u = __builtin_bit_cast(unsigned, f);
  u = u + 0x7fffu + ((u >> 16) & 1u);
  return (short)(u >> 16);
}

DEV float fexp2(float x) {  // raw v_exp_f32 (2^x)
  float r;
  asm("v_exp_f32 %0, %1" : "=v"(r) : "v"(x));
  return r;
}
DEV float frcp(float x) {
  float r;
  asm("v_rcp_f32 %0, %1" : "=v"(r) : "v"(x));
  return r;
}
DEV unsigned cvtpk(float a, float b) {  // {lo:bf16(a), hi:bf16(b)}
  unsigned r;
  asm("v_cvt_pk_bf16_f32 %0, %1, %2" : "=v"(r) : "v"(a), "v"(b));
  return r;
}

DEV void gload_lds16(const void* g, void* l) {
  __builtin_amdgcn_global_load_lds((const __attribute__((address_space(1))) void*)g,
                                   (__attribute__((address_space(3))) void*)l, 16, 0, 0);
}

DEV void cast_range(const float* __restrict__ in, unsigned long long* __restrict__ out,
                    int n4, int start, int stride) {
  for (int i = start; i < n4; i += stride) {
    const float4 f = ((const float4*)in)[i];
    unsigned long long a = (unsigned long long)(unsigned short)f2bf(f.x)
        | ((unsigned long long)(unsigned short)f2bf(f.y) << 16)
        | ((unsigned long long)(unsigned short)f2bf(f.z) << 32)
        | ((unsigned long long)(unsigned short)f2bf(f.w) << 48);
    out[i] = a;
  }
}

// One launch, three buffers (x, w_qkv, w_out)
__global__ __launch_bounds__(256)
void cast3_f32_bf16(const float* __restrict__ x, unsigned long long* __restrict__ ox, int nx4,
                    const float* __restrict__ wq, unsigned long long* __restrict__ owq, int nwq4,
                    const float* __restrict__ wo, unsigned long long* __restrict__ owo, int nwo4) {
  const int start = blockIdx.x * 256 + threadIdx.x;
  const int stride = gridDim.x * 256;
  cast_range(x, ox, nx4, start, stride);
  cast_range(wq, owq, nwq4, start, stride);
  cast_range(wo, owo, nwo4, start, stride);
}

// C = A[M,K] * Bw[N,K]^T + bias.  EPI=0: scatter to Q/K/V bf16 ws. EPI=1: f32 out.
// v10: double-buffered LDS (2-phase: stage t+1 after top barrier, compute t;
// one barrier/tile) + XOR-swizzled staging (pre-swizzled global source, linear
// LDS dest, ^(row&7) on read slot) -> conflict-free ds_read_b128.
// Q pre-scaled by (1/sqrt(HD))*log2(e): attention softmax runs in exp2 domain.
// V stored with per-64 quad permutation tau so attention PV B-frag is one b128.
template<int EPI>
__global__ __launch_bounds__(256)
void gemm_bt(const short* __restrict__ A, const short* __restrict__ Bw,
             const float* __restrict__ bias,
             short* __restrict__ qo, short* __restrict__ ko, short* __restrict__ vo,
             float* __restrict__ co,
             int M, int N, int K) {
  __shared__ short sA[2][128 * 64];
  __shared__ short sB[2][128 * 64];
  const int lane = threadIdx.x & 63;
  const int wv = threadIdx.x >> 6;
  const int wm = wv >> 1, wn = wv & 1;
  const int m0 = blockIdx.y * 128;
  const int n0 = blockIdx.x * 128;
  const int lr = lane & 15;
  const int lg = lane >> 4;
  const int lm = lr & 7;

  // staging geometry: 16 chunks/tile (c = i*4+wv), element e = c*64+lane,
  // tile row = e>>3 (8 x 16B per 128B row), LDS dest linear at e*16B,
  // global source chunk pre-swizzled (e&7)^(row&7).
  int srow[4], soff[4], doff[4];
#pragma unroll
  for (int i = 0; i < 4; ++i) {
    const int e = (i * 4 + wv) * 64 + lane;
    const int row = e >> 3;
    srow[i] = row;
    soff[i] = ((e & 7) ^ (row & 7)) * 8;   // shorts
    doff[i] = e * 8;                        // shorts
  }

  f32x4 acc[4][4] = {};
  const int nkt = K >> 6;

  // prologue: stage k-tile 0 into buffer 0
#pragma unroll
  for (int i = 0; i < 4; ++i) {
    gload_lds16(A  + (size_t)(m0 + srow[i]) * K + soff[i], &sA[0][doff[i]]);
    gload_lds16(Bw + (size_t)(n0 + srow[i]) * K + soff[i], &sB[0][doff[i]]);
  }

  int cur = 0;
  for (int kt = 0; kt < nkt; ++kt) {
    __syncthreads();   // buf[cur] staged (vmcnt drained); prev reads done
    if (kt + 1 < nkt) {
      const int k1 = (kt + 1) << 6;
#pragma unroll
      for (int i = 0; i < 4; ++i) {
        gload_lds16(A  + (size_t)(m0 + srow[i]) * K + k1 + soff[i], &sA[cur ^ 1][doff[i]]);
        gload_lds16(Bw + (size_t)(n0 + srow[i]) * K + k1 + soff[i], &sB[cur ^ 1][doff[i]]);
      }
    }
#pragma unroll
    for (int ks = 0; ks < 2; ++ks) {
      const int slot = (((ks << 2) + lg) ^ lm) * 8;
      bf16x8 af[4], bf_[4];
#pragma unroll
      for (int i = 0; i < 4; ++i) {
        af[i]  = *(const bf16x8*)&sA[cur][(wm * 64 + i * 16 + lr) * 64 + slot];
        bf_[i] = *(const bf16x8*)&sB[cur][(wn * 64 + i * 16 + lr) * 64 + slot];
      }
#pragma unroll
      for (int i = 0; i < 4; ++i)
#pragma unroll
        for (int j = 0; j < 4; ++j)
          acc[i][j] = __builtin_amdgcn_mfma_f32_16x16x32_bf16(af[i], bf_[j], acc[i][j], 0, 0, 0);
    }
    cur ^= 1;
  }

#pragma unroll
  for (int i = 0; i < 4; ++i) {
#pragma unroll
    for (int j = 0; j < 4; ++j) {
#pragma unroll
      for (int r = 0; r < 4; ++r) {
        const int row = m0 + wm * 64 + i * 16 + lg * 4 + r;
        const int col = n0 + wn * 64 + j * 16 + lr;
        float v = acc[i][j][r] + bias[col];
        if (EPI == 0) {
          const int part = col >> 10, oo = col & 1023;
          const int h = oo >> 6, d = oo & 63;
          const int bb = row >> 11, s = row & 2047;
          if (part == 0)
            qo[(((size_t)bb * HH + h) * SS + s) * HDD + d] = f2bf(v * 0.18033688f); // 0.125*log2(e)
          else if (part == 1)
            ko[(((size_t)bb * HH + h) * SS + s) * HDD + d] = f2bf(v);
          else {
            const int q = (s >> 2) & 15;
            const int tau = (q & 8) | ((q & 3) << 1) | ((q >> 2) & 1);
            vo[(((size_t)bb * HH + h) * HDD + d) * SS + (s & ~63) + (tau << 2) + (s & 3)] = f2bf(v);
          }
        } else {
          co[(size_t)row * N + col] = v;
        }
      }
    }
  }
}

// Flash attention v9 (unchanged from round 9): QBLK=128, swapped-operand QK^T,
// P in registers, tau-interleaved V -> single-b128 PV reads, K/V dbuf LDS,
// exp2 softmax, defer-max. grid (NQT/2, B*H), paired q-tiles {bx, NQT-1-bx}.
__global__ __launch_bounds__(256)
void attn_fwd(const short* __restrict__ Q, const short* __restrict__ K,
              const short* __restrict__ V, short* __restrict__ Y) {
  __shared__ short sK[2][64 * 64];
  __shared__ short sV[2][64 * 64];
  const int bh = blockIdx.y;
  const int tid = threadIdx.x, lane = tid & 63, w = tid >> 6;
  const size_t bqk = (size_t)bh * (SS * HDD);
  const size_t bv  = (size_t)bh * (HDD * SS);
  const int b = bh >> 4, h = bh & 15;
  const int lr = lane & 15;        // q-col index within 16-group
  const int lg = lane >> 4;        // k-group
  const int lm = lr & 7;           // swizzle row bits

  const int e0 = w * 64 + lane;
  const int e1 = 256 + e0;
  const int r0 = e0 >> 3, s0 = ((e0 & 7) ^ (r0 & 7)) * 8;
  const int r1 = e1 >> 3, s1 = ((e1 & 7) ^ (r1 & 7)) * 8;

  for (int qsel = 0; qsel < 2; ++qsel) {
    const int qt = qsel ? (NQT - 1 - blockIdx.x) : blockIdx.x;
    const int q0 = qt * 128;
    const int nkv = 2 * qt + 2;

    __syncthreads();   // protect buffer re-stage vs previous q-tile's reads

    {
      const short* gK = K + bqk;
      const short* gV = V + bv;
      gload_lds16(gK + (size_t)r0 * HDD + s0, &sK[0][e0 * 8]);
      gload_lds16(gV + (size_t)r0 * SS + s0, &sV[0][e0 * 8]);
      gload_lds16(gK + (size_t)r1 * HDD + s1, &sK[0][e1 * 8]);
      gload_lds16(gV + (size_t)r1 * SS + s1, &sV[0][e1 * 8]);
    }

    const int qbase = q0 + w * 32;
    bf16x8 qf[2][2];
#pragma unroll
    for (int g = 0; g < 2; ++g)
#pragma unroll
      for (int ks = 0; ks < 2; ++ks)
        qf[g][ks] = *(const bf16x8*)&Q[bqk + (size_t)(qbase + g * 16 + lr) * HDD + ks * 32 + lg * 8];

    f32x4 accO[2][4] = {};
    float m_[2] = {-1e30f, -1e30f}, l_[2] = {0.f, 0.f};

    int cur = 0;
    for (int kt = 0; kt < nkv; ++kt) {
      const int kc0 = kt * 64;
      __syncthreads();   // staged tile ready (vmcnt drained); prev reads done
      if (kt < nkv - 1) {
        const short* gK = K + bqk + (size_t)(kc0 + 64) * 64;
        const short* gV = V + bv + kc0 + 64;
        gload_lds16(gK + (size_t)r0 * HDD + s0, &sK[cur ^ 1][e0 * 8]);
        gload_lds16(gV + (size_t)r0 * SS + s0, &sV[cur ^ 1][e0 * 8]);
        gload_lds16(gK + (size_t)r1 * HDD + s1, &sK[cur ^ 1][e1 * 8]);
        gload_lds16(gV + (size_t)r1 * SS + s1, &sV[cur ^ 1][e1 * 8]);
      }

      f32x4 st[2][4] = {};
#pragma unroll
      for (int ks = 0; ks < 2; ++ks) {
#pragma unroll
        for (int nf = 0; nf < 4; ++nf) {
          const int row = nf * 16 + lr;
          const bf16x8 kf = *(const bf16x8*)&sK[cur][row * 64 + (((ks << 2) + lg) ^ lm) * 8];
          st[0][nf] = __builtin_amdgcn_mfma_f32_16x16x32_bf16(kf, qf[0][ks], st[0][nf], 0, 0, 0);
          st[1][nf] = __builtin_amdgcn_mfma_f32_16x16x32_bf16(kf, qf[1][ks], st[1][nf], 0, 0, 0);
        }
      }
      if (kt >= nkv - 2) {   // diagonal tiles: causal mask (k > q)
#pragma unroll
        for (int g = 0; g < 2; ++g) {
          const int q = qbase + g * 16 + lr;
#pragma unroll
          for (int nf = 0; nf < 4; ++nf)
#pragma unroll
            for (int r = 0; r < 4; ++r) {
              const int k = kc0 + nf * 16 + lg * 4 + r;
              if (k > q) st[g][nf][r] = -1e30f;
            }
        }
      }

      unsigned u[2][4][2];
#pragma unroll
      for (int g = 0; g < 2; ++g) {
        float rm = -1e30f;
#pragma unroll
        for (int r = 0; r < 4; ++r)
          rm = fmaxf(rm, fmaxf(fmaxf(st[g][0][r], st[g][1][r]), fmaxf(st[g][2][r], st[g][3][r])));
        rm = fmaxf(rm, __shfl_xor(rm, 16));
        rm = fmaxf(rm, __shfl_xor(rm, 32));

        const bool need = rm > m_[g] + 11.5416f;
        if (__any(need)) {
          const float mn = fmaxf(m_[g], rm);
          const float scale = fexp2(m_[g] - mn);
          m_[g] = mn;
          l_[g] *= scale;
#pragma unroll
          for (int r = 0; r < 4; ++r) {
            const float scl = __shfl(scale, (lane & 48) + (lg << 2) + r);
#pragma unroll
            for (int df = 0; df < 4; ++df) accO[g][df][r] *= scl;
          }
        }

        float rs = 0.f;
#pragma unroll
        for (int nf = 0; nf < 4; ++nf)
#pragma unroll
          for (int r = 0; r < 4; ++r) {
            const float p = fexp2(st[g][nf][r] - m_[g]);
            st[g][nf][r] = p;
            rs += p;
          }
        rs += __shfl_xor(rs, 16);
        rs += __shfl_xor(rs, 32);
        l_[g] += rs;

#pragma unroll
        for (int nf = 0; nf < 4; ++nf) {
          u[g][nf][0] = cvtpk(st[g][nf][0], st[g][nf][1]);
          u[g][nf][1] = cvtpk(st[g][nf][2], st[g][nf][3]);
        }
      }

#pragma unroll
      for (int c = 0; c < 2; ++c) {
        int4 pw0, pw1;
        pw0.x = (int)u[0][2 * c][0]; pw0.y = (int)u[0][2 * c][1];
        pw0.z = (int)u[0][2 * c + 1][0]; pw0.w = (int)u[0][2 * c + 1][1];
        pw1.x = (int)u[1][2 * c][0]; pw1.y = (int)u[1][2 * c][1];
        pw1.z = (int)u[1][2 * c + 1][0]; pw1.w = (int)u[1][2 * c + 1][1];
        const bf16x8 pf0 = __builtin_bit_cast(bf16x8, pw0);
        const bf16x8 pf1 = __builtin_bit_cast(bf16x8, pw1);
        const int slot = (((c << 2) + lg) ^ lm) * 8;
#pragma unroll
        for (int df = 0; df < 4; ++df) {
          const bf16x8 vf = *(const bf16x8*)&sV[cur][(df * 16 + lr) * 64 + slot];
          accO[0][df] = __builtin_amdgcn_mfma_f32_16x16x32_bf16(pf0, vf, accO[0][df], 0, 0, 0);
          accO[1][df] = __builtin_amdgcn_mfma_f32_16x16x32_bf16(pf1, vf, accO[1][df], 0, 0, 0);
        }
      }
      cur ^= 1;
    }

#pragma unroll
    for (int g = 0; g < 2; ++g)
#pragma unroll
      for (int r = 0; r < 4; ++r) {
        const float lv = __shfl(l_[g], (lane & 48) + (lg << 2) + r);
        const float inv = frcp(lv);
        const int srow2 = qbase + g * 16 + lg * 4 + r;
#pragma unroll
        for (int df = 0; df < 4; ++df) {
          const int dcol = h * HDD + df * 16 + lr;
          Y[((size_t)b * SS + srow2) * DD + dcol] = f2bf(accO[g][df][r] * inv);
        }
      }
  }
}

extern "C" void kernel_launch(void* const* d_in, const int* in_sizes, int n_in,
                              void* d_out, int out_size, void* d_ws, size_t ws_size,
                              hipStream_t stream) {
  const float* x     = (const float*)d_in[0];
  const float* w_qkv = (const float*)d_in[1];
  const float* b_qkv = (const float*)d_in[2];
  const float* w_out = (const float*)d_in[3];
  const float* b_out = (const float*)d_in[4];
  float* out = (float*)d_out;

  const size_t nx = (size_t)MM * DD;        // 8388608
  const size_t nwq = (size_t)3 * DD * DD;   // 3145728
  const size_t nwo = (size_t)DD * DD;       // 1048576

  short* x_bf    = (short*)d_ws;
  short* wqkv_bf = x_bf + nx;
  short* wout_bf = wqkv_bf + nwq;
  short* q_ws    = wout_bf + nwo;
  short* k_ws    = q_ws + nx;
  short* v_ws    = k_ws + nx;
  short* y_ws    = v_ws + nx;

  cast3_f32_bf16<<<dim3(2048), dim3(256), 0, stream>>>(
      x, (unsigned long long*)x_bf, (int)(nx / 4),
      w_qkv, (unsigned long long*)wqkv_bf, (int)(nwq / 4),
      w_out, (unsigned long long*)wout_bf, (int)(nwo / 4));

  gemm_bt<0><<<dim3(3 * DD / 128, MM / 128), dim3(256), 0, stream>>>(
      x_bf, wqkv_bf, b_qkv, q_ws, k_ws, v_ws, nullptr, MM, 3 * DD, DD);

  attn_fwd<<<dim3(NQT / 2, BB * HH), dim3(256), 0, stream>>>(q_ws, k_ws, v_ws, y_ws);

  gemm_bt<1><<<dim3(DD / 128, MM / 128), dim3(256), 0, stream>>>(
      y_ws, wout_bf, b_out, nullptr, nullptr, nullptr, out, MM, DD, DD);
}

// Round 11
// 190.897 us; speedup vs baseline: 1.4209x; 1.0380x over previous
//
#include <hip/hip_runtime.h>
#include <hip/hip_bf16.h>

#define DEV __device__ __forceinline__

typedef __attribute__((ext_vector_type(8))) short bf16x8;
typedef __attribute__((ext_vector_type(4))) float f32x4;

// Problem constants
#define BB 4
#define SS 2048
#define DD 1024
#define HH 16
#define HDD 64
#define MM (BB * SS)   // 8192
#define NT (SS / 64)   // 32 kv-tiles per (b,h)
#define NQT (SS / 128) // 16 q-tiles of 128 rows

DEV short f2bf(float f) {
  unsigned u = __builtin_bit_cast(unsigned, f);
  u = u + 0x7fffu + ((u >> 16) & 1u);
  return (short)(u >> 16);
}

DEV float fexp2(float x) {  // raw v_exp_f32 (2^x)
  float r;
  asm("v_exp_f32 %0, %1" : "=v"(r) : "v"(x));
  return r;
}
DEV float frcp(float x) {
  float r;
  asm("v_rcp_f32 %0, %1" : "=v"(r) : "v"(x));
  return r;
}
DEV unsigned cvtpk(float a, float b) {  // {lo:bf16(a), hi:bf16(b)}
  unsigned r;
  asm("v_cvt_pk_bf16_f32 %0, %1, %2" : "=v"(r) : "v"(a), "v"(b));
  return r;
}

DEV void gload_lds16(const void* g, void* l) {
  __builtin_amdgcn_global_load_lds((const __attribute__((address_space(1))) void*)g,
                                   (__attribute__((address_space(3))) void*)l, 16, 0, 0);
}

// T1: XCD-chunked bijective blockIdx swizzle (m157; valid since nwg % 8 == 0).
// Block dispatched o-th runs on XCD o%8; give it work item (o%8)*(nwg/8)+o/8
// so each XCD owns a CONTIGUOUS chunk of the linearized grid -> L2 locality.
DEV int2 xcd_swizzle() {
  const int nx = gridDim.x;
  const int nwg = nx * gridDim.y;
  const int o = blockIdx.y * nx + blockIdx.x;
  const int wid = (o & 7) * (nwg >> 3) + (o >> 3);
  int2 r; r.x = wid % nx; r.y = wid / nx;
  return r;
}

DEV void cast_range(const float* __restrict__ in, unsigned long long* __restrict__ out,
                    int n4, int start, int stride) {
  for (int i = start; i < n4; i += stride) {
    const float4 f = ((const float4*)in)[i];
    unsigned long long a = (unsigned long long)(unsigned short)f2bf(f.x)
        | ((unsigned long long)(unsigned short)f2bf(f.y) << 16)
        | ((unsigned long long)(unsigned short)f2bf(f.z) << 32)
        | ((unsigned long long)(unsigned short)f2bf(f.w) << 48);
    out[i] = a;
  }
}

// One launch, three buffers (x, w_qkv, w_out)
__global__ __launch_bounds__(256)
void cast3_f32_bf16(const float* __restrict__ x, unsigned long long* __restrict__ ox, int nx4,
                    const float* __restrict__ wq, unsigned long long* __restrict__ owq, int nwq4,
                    const float* __restrict__ wo, unsigned long long* __restrict__ owo, int nwo4) {
  const int start = blockIdx.x * 256 + threadIdx.x;
  const int stride = gridDim.x * 256;
  cast_range(x, ox, nx4, start, stride);
  cast_range(wq, owq, nwq4, start, stride);
  cast_range(wo, owo, nwo4, start, stride);
}

// C = A[M,K] * Bw[N,K]^T + bias.  EPI=0: scatter to Q/K/V bf16 ws. EPI=1: f32 out.
// Double-buffered LDS (2-phase), XOR-swizzled staging (conflict-free b128 reads),
// T1 XCD-chunked block swizzle (each XCD = 8 contiguous M-rows -> A panels L2-fit).
// Q pre-scaled by (1/sqrt(HD))*log2(e): attention softmax runs in exp2 domain.
// V stored with per-64 quad permutation tau so attention PV B-frag is one b128.
template<int EPI>
__global__ __launch_bounds__(256)
void gemm_bt(const short* __restrict__ A, const short* __restrict__ Bw,
             const float* __restrict__ bias,
             short* __restrict__ qo, short* __restrict__ ko, short* __restrict__ vo,
             float* __restrict__ co,
             int M, int N, int K) {
  __shared__ short sA[2][128 * 64];
  __shared__ short sB[2][128 * 64];
  const int lane = threadIdx.x & 63;
  const int wv = threadIdx.x >> 6;
  const int wm = wv >> 1, wn = wv & 1;
  const int2 sw = xcd_swizzle();
  const int m0 = sw.y * 128;
  const int n0 = sw.x * 128;
  const int lr = lane & 15;
  const int lg = lane >> 4;
  const int lm = lr & 7;

  // staging geometry: 16 chunks/tile (c = i*4+wv), element e = c*64+lane,
  // tile row = e>>3, LDS dest linear at e*16B, global source chunk (e&7)^(row&7).
  int srow[4], soff[4], doff[4];
#pragma unroll
  for (int i = 0; i < 4; ++i) {
    const int e = (i * 4 + wv) * 64 + lane;
    const int row = e >> 3;
    srow[i] = row;
    soff[i] = ((e & 7) ^ (row & 7)) * 8;   // shorts
    doff[i] = e * 8;                        // shorts
  }

  f32x4 acc[4][4] = {};
  const int nkt = K >> 6;

  // prologue: stage k-tile 0 into buffer 0
#pragma unroll
  for (int i = 0; i < 4; ++i) {
    gload_lds16(A  + (size_t)(m0 + srow[i]) * K + soff[i], &sA[0][doff[i]]);
    gload_lds16(Bw + (size_t)(n0 + srow[i]) * K + soff[i], &sB[0][doff[i]]);
  }

  int cur = 0;
  for (int kt = 0; kt < nkt; ++kt) {
    __syncthreads();   // buf[cur] staged (vmcnt drained); prev reads done
    if (kt + 1 < nkt) {
      const int k1 = (kt + 1) << 6;
#pragma unroll
      for (int i = 0; i < 4; ++i) {
        gload_lds16(A  + (size_t)(m0 + srow[i]) * K + k1 + soff[i], &sA[cur ^ 1][doff[i]]);
        gload_lds16(Bw + (size_t)(n0 + srow[i]) * K + k1 + soff[i], &sB[cur ^ 1][doff[i]]);
      }
    }
#pragma unroll
    for (int ks = 0; ks < 2; ++ks) {
      const int slot = (((ks << 2) + lg) ^ lm) * 8;
      bf16x8 af[4], bf_[4];
#pragma unroll
      for (int i = 0; i < 4; ++i) {
        af[i]  = *(const bf16x8*)&sA[cur][(wm * 64 + i * 16 + lr) * 64 + slot];
        bf_[i] = *(const bf16x8*)&sB[cur][(wn * 64 + i * 16 + lr) * 64 + slot];
      }
#pragma unroll
      for (int i = 0; i < 4; ++i)
#pragma unroll
        for (int j = 0; j < 4; ++j)
          acc[i][j] = __builtin_amdgcn_mfma_f32_16x16x32_bf16(af[i], bf_[j], acc[i][j], 0, 0, 0);
    }
    cur ^= 1;
  }

#pragma unroll
  for (int i = 0; i < 4; ++i) {
#pragma unroll
    for (int j = 0; j < 4; ++j) {
#pragma unroll
      for (int r = 0; r < 4; ++r) {
        const int row = m0 + wm * 64 + i * 16 + lg * 4 + r;
        const int col = n0 + wn * 64 + j * 16 + lr;
        float v = acc[i][j][r] + bias[col];
        if (EPI == 0) {
          const int part = col >> 10, oo = col & 1023;
          const int h = oo >> 6, d = oo & 63;
          const int bb = row >> 11, s = row & 2047;
          if (part == 0)
            qo[(((size_t)bb * HH + h) * SS + s) * HDD + d] = f2bf(v * 0.18033688f); // 0.125*log2(e)
          else if (part == 1)
            ko[(((size_t)bb * HH + h) * SS + s) * HDD + d] = f2bf(v);
          else {
            const int q = (s >> 2) & 15;
            const int tau = (q & 8) | ((q & 3) << 1) | ((q >> 2) & 1);
            vo[(((size_t)bb * HH + h) * HDD + d) * SS + (s & ~63) + (tau << 2) + (s & 3)] = f2bf(v);
          }
        } else {
          co[(size_t)row * N + col] = v;
        }
      }
    }
  }
}

// Flash attention (round-9 structure + T1 swizzle): QBLK=128, swapped-operand
// QK^T, P in registers, tau-interleaved V -> single-b128 PV reads, K/V dbuf
// LDS, exp2 softmax, defer-max. grid (NQT/2, B*H) swizzled so each XCD owns
// 8 contiguous heads (K/V working set ~4MB = L2-resident).
__global__ __launch_bounds__(256)
void attn_fwd(const short* __restrict__ Q, const short* __restrict__ K,
              const short* __restrict__ V, short* __restrict__ Y) {
  __shared__ short sK[2][64 * 64];
  __shared__ short sV[2][64 * 64];
  const int2 sw = xcd_swizzle();
  const int bh = sw.y;
  const int bx = sw.x;
  const int tid = threadIdx.x, lane = tid & 63, w = tid >> 6;
  const size_t bqk = (size_t)bh * (SS * HDD);
  const size_t bv  = (size_t)bh * (HDD * SS);
  const int b = bh >> 4, h = bh & 15;
  const int lr = lane & 15;        // q-col index within 16-group
  const int lg = lane >> 4;        // k-group
  const int lm = lr & 7;           // swizzle row bits

  const int e0 = w * 64 + lane;
  const int e1 = 256 + e0;
  const int r0 = e0 >> 3, s0 = ((e0 & 7) ^ (r0 & 7)) * 8;
  const int r1 = e1 >> 3, s1 = ((e1 & 7) ^ (r1 & 7)) * 8;

  for (int qsel = 0; qsel < 2; ++qsel) {
    const int qt = qsel ? (NQT - 1 - bx) : bx;
    const int q0 = qt * 128;
    const int nkv = 2 * qt + 2;

    __syncthreads();   // protect buffer re-stage vs previous q-tile's reads

    {
      const short* gK = K + bqk;
      const short* gV = V + bv;
      gload_lds16(gK + (size_t)r0 * HDD + s0, &sK[0][e0 * 8]);
      gload_lds16(gV + (size_t)r0 * SS + s0, &sV[0][e0 * 8]);
      gload_lds16(gK + (size_t)r1 * HDD + s1, &sK[0][e1 * 8]);
      gload_lds16(gV + (size_t)r1 * SS + s1, &sV[0][e1 * 8]);
    }

    const int qbase = q0 + w * 32;
    bf16x8 qf[2][2];
#pragma unroll
    for (int g = 0; g < 2; ++g)
#pragma unroll
      for (int ks = 0; ks < 2; ++ks)
        qf[g][ks] = *(const bf16x8*)&Q[bqk + (size_t)(qbase + g * 16 + lr) * HDD + ks * 32 + lg * 8];

    f32x4 accO[2][4] = {};
    float m_[2] = {-1e30f, -1e30f}, l_[2] = {0.f, 0.f};

    int cur = 0;
    for (int kt = 0; kt < nkv; ++kt) {
      const int kc0 = kt * 64;
      __syncthreads();   // staged tile ready (vmcnt drained); prev reads done
      if (kt < nkv - 1) {
        const short* gK = K + bqk + (size_t)(kc0 + 64) * 64;
        const short* gV = V + bv + kc0 + 64;
        gload_lds16(gK + (size_t)r0 * HDD + s0, &sK[cur ^ 1][e0 * 8]);
        gload_lds16(gV + (size_t)r0 * SS + s0, &sV[cur ^ 1][e0 * 8]);
        gload_lds16(gK + (size_t)r1 * HDD + s1, &sK[cur ^ 1][e1 * 8]);
        gload_lds16(gV + (size_t)r1 * SS + s1, &sV[cur ^ 1][e1 * 8]);
      }

      f32x4 st[2][4] = {};
#pragma unroll
      for (int ks = 0; ks < 2; ++ks) {
#pragma unroll
        for (int nf = 0; nf < 4; ++nf) {
          const int row = nf * 16 + lr;
          const bf16x8 kf = *(const bf16x8*)&sK[cur][row * 64 + (((ks << 2) + lg) ^ lm) * 8];
          st[0][nf] = __builtin_amdgcn_mfma_f32_16x16x32_bf16(kf, qf[0][ks], st[0][nf], 0, 0, 0);
          st[1][nf] = __builtin_amdgcn_mfma_f32_16x16x32_bf16(kf, qf[1][ks], st[1][nf], 0, 0, 0);
        }
      }
      if (kt >= nkv - 2) {   // diagonal tiles: causal mask (k > q)
#pragma unroll
        for (int g = 0; g < 2; ++g) {
          const int q = qbase + g * 16 + lr;
#pragma unroll
          for (int nf = 0; nf < 4; ++nf)
#pragma unroll
            for (int r = 0; r < 4; ++r) {
              const int k = kc0 + nf * 16 + lg * 4 + r;
              if (k > q) st[g][nf][r] = -1e30f;
            }
        }
      }

      unsigned u[2][4][2];
#pragma unroll
      for (int g = 0; g < 2; ++g) {
        float rm = -1e30f;
#pragma unroll
        for (int r = 0; r < 4; ++r)
          rm = fmaxf(rm, fmaxf(fmaxf(st[g][0][r], st[g][1][r]), fmaxf(st[g][2][r], st[g][3][r])));
        rm = fmaxf(rm, __shfl_xor(rm, 16));
        rm = fmaxf(rm, __shfl_xor(rm, 32));

        const bool need = rm > m_[g] + 11.5416f;
        if (__any(need)) {
          const float mn = fmaxf(m_[g], rm);
          const float scale = fexp2(m_[g] - mn);
          m_[g] = mn;
          l_[g] *= scale;
#pragma unroll
          for (int r = 0; r < 4; ++r) {
            const float scl = __shfl(scale, (lane & 48) + (lg << 2) + r);
#pragma unroll
            for (int df = 0; df < 4; ++df) accO[g][df][r] *= scl;
          }
        }

        float rs = 0.f;
#pragma unroll
        for (int nf = 0; nf < 4; ++nf)
#pragma unroll
          for (int r = 0; r < 4; ++r) {
            const float p = fexp2(st[g][nf][r] - m_[g]);
            st[g][nf][r] = p;
            rs += p;
          }
        rs += __shfl_xor(rs, 16);
        rs += __shfl_xor(rs, 32);
        l_[g] += rs;

#pragma unroll
        for (int nf = 0; nf < 4; ++nf) {
          u[g][nf][0] = cvtpk(st[g][nf][0], st[g][nf][1]);
          u[g][nf][1] = cvtpk(st[g][nf][2], st[g][nf][3]);
        }
      }

#pragma unroll
      for (int c = 0; c < 2; ++c) {
        int4 pw0, pw1;
        pw0.x = (int)u[0][2 * c][0]; pw0.y = (int)u[0][2 * c][1];
        pw0.z = (int)u[0][2 * c + 1][0]; pw0.w = (int)u[0][2 * c + 1][1];
        pw1.x = (int)u[1][2 * c][0]; pw1.y = (int)u[1][2 * c][1];
        pw1.z = (int)u[1][2 * c + 1][0]; pw1.w = (int)u[1][2 * c + 1][1];
        const bf16x8 pf0 = __builtin_bit_cast(bf16x8, pw0);
        const bf16x8 pf1 = __builtin_bit_cast(bf16x8, pw1);
        const int slot = (((c << 2) + lg) ^ lm) * 8;
#pragma unroll
        for (int df = 0; df < 4; ++df) {
          const bf16x8 vf = *(const bf16x8*)&sV[cur][(df * 16 + lr) * 64 + slot];
          accO[0][df] = __builtin_amdgcn_mfma_f32_16x16x32_bf16(pf0, vf, accO[0][df], 0, 0, 0);
          accO[1][df] = __builtin_amdgcn_mfma_f32_16x16x32_bf16(pf1, vf, accO[1][df], 0, 0, 0);
        }
      }
      cur ^= 1;
    }

#pragma unroll
    for (int g = 0; g < 2; ++g)
#pragma unroll
      for (int r = 0; r < 4; ++r) {
        const float lv = __shfl(l_[g], (lane & 48) + (lg << 2) + r);
        const float inv = frcp(lv);
        const int srow2 = qbase + g * 16 + lg * 4 + r;
#pragma unroll
        for (int df = 0; df < 4; ++df) {
          const int dcol = h * HDD + df * 16 + lr;
          Y[((size_t)b * SS + srow2) * DD + dcol] = f2bf(accO[g][df][r] * inv);
        }
      }
  }
}

extern "C" void kernel_launch(void* const* d_in, const int* in_sizes, int n_in,
                              void* d_out, int out_size, void* d_ws, size_t ws_size,
                              hipStream_t stream) {
  const float* x     = (const float*)d_in[0];
  const float* w_qkv = (const float*)d_in[1];
  const float* b_qkv = (const float*)d_in[2];
  const float* w_out = (const float*)d_in[3];
  const float* b_out = (const float*)d_in[4];
  float* out = (float*)d_out;

  const size_t nx = (size_t)MM * DD;        // 8388608
  const size_t nwq = (size_t)3 * DD * DD;   // 3145728
  const size_t nwo = (size_t)DD * DD;       // 1048576

  short* x_bf    = (short*)d_ws;
  short* wqkv_bf = x_bf + nx;
  short* wout_bf = wqkv_bf + nwq;
  short* q_ws    = wout_bf + nwo;
  short* k_ws    = q_ws + nx;
  short* v_ws    = k_ws + nx;
  short* y_ws    = v_ws + nx;

  cast3_f32_bf16<<<dim3(2048), dim3(256), 0, stream>>>(
      x, (unsigned long long*)x_bf, (int)(nx / 4),
      w_qkv, (unsigned long long*)wqkv_bf, (int)(nwq / 4),
      w_out, (unsigned long long*)wout_bf, (int)(nwo / 4));

  gemm_bt<0><<<dim3(3 * DD / 128, MM / 128), dim3(256), 0, stream>>>(
      x_bf, wqkv_bf, b_qkv, q_ws, k_ws, v_ws, nullptr, MM, 3 * DD, DD);

  attn_fwd<<<dim3(NQT / 2, BB * HH), dim3(256), 0, stream>>>(q_ws, k_ws, v_ws, y_ws);

  gemm_bt<1><<<dim3(DD / 128, MM / 128), dim3(256), 0, stream>>>(
      y_ws, wout_bf, b_out, nullptr, nullptr, nullptr, out, MM, DD, DD);
}